// Round 9
// baseline (212.379 us; speedup 1.0000x reference)
//
#include <hip/hip_runtime.h>
#include <math.h>

// Problem dims
// B=4, N_IN=128, NODE=32, L=256, N_HID=D_IN=64, D_STATE=128, DT_RANK=4, N_OUT=128
// R = B*NODE = 128 rows, each row independent; L sequential only in the scan (k3).
//
// R7 change: k3 was DS-pipe-bound (R6 arithmetic: ~8 DS ops/tt/wave x 256tt x
// 16 waves/CU ~ 111us ~= measured 117us; bank conflicts 0 -> raw DS throughput).
// New k3: no LDS at all (direct global reads, L1-broadcast-friendly), and the
// 16-lane s-reduction done with DPP row_ror rotate-adds (VALU pipe) instead of
// __shfl_xor (ds_swizzle). Zero barriers, zero DS ops. k1/k2/k4/k5 unchanged.

__device__ __forceinline__ float silu_f(float v) { return v / (1.f + __expf(-v)); }
__device__ __forceinline__ float softplus_f(float v) { return v > 20.f ? v : log1pf(__expf(v)); }

// ---------------------------------------------------------------------------
// K1: X = in @ w_in.T + b_in ; XZ = X @ in_proj_w.T -> XM (first 64), Z (last 64)
// grid 512 = 128 rows x 4 t-tiles(64), block 256
// ---------------------------------------------------------------------------
__global__ __launch_bounds__(256) void k1_proj(
    const float* __restrict__ inp, const float* __restrict__ w_in,
    const float* __restrict__ b_in, const float* __restrict__ ipw,
    float* __restrict__ XM, float* __restrict__ Zb)
{
  __shared__ float sIN[128*64];   // [i=128][t=64]
  __shared__ float sW[64*68];     // staged weight tile [row][k], stride 68
  __shared__ float sXT[64*68];    // X transposed [h][t], stride 68
  const int bid = blockIdx.x;
  const int r = bid >> 2, tb = bid & 3;
  const int b = r >> 5, node = r & 31;
  const int t0 = tb * 64;
  const int tid = threadIdx.x;
  const int tg = tid & 15, vg = tid >> 4;
  const int tl0 = tg * 4, v0 = vg * 4;

  for (int e = tid; e < 128*64; e += 256) {
    int i = e >> 6, t = e & 63;
    sIN[e] = inp[((b*128 + i)*32 + node)*256 + t0 + t];
  }

  // Phase A: X[t][h] = b_in[h] + sum_i in[i][t] * w_in[h][i]   (K=128, 2 chunks)
  float acc[4][4];
  #pragma unroll
  for (int ti = 0; ti < 4; ti++)
    #pragma unroll
    for (int j = 0; j < 4; j++) acc[ti][j] = b_in[v0 + j];

  for (int kc = 0; kc < 2; kc++) {
    __syncthreads();   // sIN ready (kc=0) / sW read-done (kc=1)
    for (int e = tid; e < 64*16; e += 256) {
      int row = e >> 4, c4 = e & 15;
      *(float4*)&sW[row*68 + c4*4] = *(const float4*)&w_in[row*128 + kc*64 + c4*4];
    }
    __syncthreads();
    for (int k4 = 0; k4 < 16; k4++) {
      float4 wv[4];
      #pragma unroll
      for (int j = 0; j < 4; j++)
        wv[j] = *(const float4*)&sW[(v0 + j)*68 + k4*4];
      #pragma unroll
      for (int kk = 0; kk < 4; kk++) {
        float4 x4 = *(const float4*)&sIN[(kc*64 + k4*4 + kk)*64 + tl0];
        #pragma unroll
        for (int j = 0; j < 4; j++) {
          float w = kk==0 ? wv[j].x : kk==1 ? wv[j].y : kk==2 ? wv[j].z : wv[j].w;
          acc[0][j] = fmaf(x4.x, w, acc[0][j]);
          acc[1][j] = fmaf(x4.y, w, acc[1][j]);
          acc[2][j] = fmaf(x4.z, w, acc[2][j]);
          acc[3][j] = fmaf(x4.w, w, acc[3][j]);
        }
      }
    }
  }
  // stash X^T into sXT[h][t]
  #pragma unroll
  for (int j = 0; j < 4; j++)
    *(float4*)&sXT[(v0 + j)*68 + tl0] =
        make_float4(acc[0][j], acc[1][j], acc[2][j], acc[3][j]);

  // Phase B: XZ[t][c] = sum_h X[h][t] * ipw[c][h]   (c: 2 passes of 64)
  for (int pass = 0; pass < 2; pass++) {
    __syncthreads();   // sXT visible (pass0) / sW read-done
    for (int e = tid; e < 64*16; e += 256) {
      int row = e >> 4, c4 = e & 15;
      *(float4*)&sW[row*68 + c4*4] = *(const float4*)&ipw[(pass*64 + row)*64 + c4*4];
    }
    __syncthreads();

    float a2[4][4];
    #pragma unroll
    for (int ti = 0; ti < 4; ti++)
      #pragma unroll
      for (int j = 0; j < 4; j++) a2[ti][j] = 0.f;

    for (int k4 = 0; k4 < 16; k4++) {
      float4 wv[4];
      #pragma unroll
      for (int j = 0; j < 4; j++)
        wv[j] = *(const float4*)&sW[(v0 + j)*68 + k4*4];
      #pragma unroll
      for (int kk = 0; kk < 4; kk++) {
        float4 x4 = *(const float4*)&sXT[(k4*4 + kk)*68 + tl0];
        #pragma unroll
        for (int j = 0; j < 4; j++) {
          float w = kk==0 ? wv[j].x : kk==1 ? wv[j].y : kk==2 ? wv[j].z : wv[j].w;
          a2[0][j] = fmaf(x4.x, w, a2[0][j]);
          a2[1][j] = fmaf(x4.y, w, a2[1][j]);
          a2[2][j] = fmaf(x4.z, w, a2[2][j]);
          a2[3][j] = fmaf(x4.w, w, a2[3][j]);
        }
      }
    }

    float* dst = (pass == 0) ? XM : Zb;
    #pragma unroll
    for (int ti = 0; ti < 4; ti++)
      *(float4*)&dst[(r*256 + t0 + tl0 + ti)*64 + v0] =
          make_float4(a2[ti][0], a2[ti][1], a2[ti][2], a2[ti][3]);
  }
}

// ---------------------------------------------------------------------------
// K2: conv+silu -> XC ; dbc = xc @ x_proj_w.T -> (dt | B | C) ; delta=softplus(...)
// grid 512 = 128 rows x 4 t-tiles(64), block 256
// ---------------------------------------------------------------------------
__global__ __launch_bounds__(256) void k2_conv_xproj(
    const float* __restrict__ XM, const float* __restrict__ convw,
    const float* __restrict__ convb, const float* __restrict__ xpw,
    const float* __restrict__ dtw, const float* __restrict__ dtb,
    float* __restrict__ XC, float* __restrict__ DELTA,
    float* __restrict__ BM, float* __restrict__ CM)
{
  __shared__ float sXM[65*64];    // [tt in -1..63][d]
  __shared__ float sXC[64*68];    // xc transposed [d][t], stride 68
  __shared__ float sW[64*68];     // staged x_proj_w tile
  __shared__ float sDT[64*5];     // dt[t][4], stride 5
  const int bid = blockIdx.x;
  const int r = bid >> 2, tb = bid & 3;
  const int t0 = tb * 64;
  const int tid = threadIdx.x;
  const int tg = tid & 15, vg = tid >> 4;
  const int tl0 = tg * 4, v0 = vg * 4;

  for (int e = tid; e < 65*64; e += 256) {
    int tt = e >> 6, d = e & 63;
    int tgl = t0 - 1 + tt;
    sXM[e] = (tgl < 0) ? 0.f : XM[(r*256 + tgl)*64 + d];
  }
  __syncthreads();

  for (int e = tid; e < 64*64; e += 256) {
    int t = e >> 6, d = e & 63;
    float c0 = convw[d*2], c1 = convw[d*2 + 1];
    float pre = fmaf(sXM[t*64 + d], c0, fmaf(sXM[(t+1)*64 + d], c1, convb[d]));
    float v = silu_f(pre);
    sXC[d*68 + t] = v;                       // transposed store
    XC[(r*256 + t0 + t)*64 + d] = v;         // coalesced global store
  }

  // dbc[t][j] = sum_d xc[d][t] * xpw[j][d],  j in 0..259 -> 5 passes of 64
  for (int pass = 0; pass < 5; pass++) {
    __syncthreads();   // sXC ready (pass0) / sW read-done
    for (int e = tid; e < 64*16; e += 256) {
      int row = e >> 4, c4 = e & 15;
      int grow = pass*64 + row;
      float4 w = (grow < 260) ? *(const float4*)&xpw[grow*64 + c4*4]
                              : make_float4(0.f, 0.f, 0.f, 0.f);
      *(float4*)&sW[row*68 + c4*4] = w;
    }
    __syncthreads();

    float acc[4][4];
    #pragma unroll
    for (int ti = 0; ti < 4; ti++)
      #pragma unroll
      for (int jj = 0; jj < 4; jj++) acc[ti][jj] = 0.f;

    for (int k4 = 0; k4 < 16; k4++) {
      float4 wv[4];
      #pragma unroll
      for (int jj = 0; jj < 4; jj++)
        wv[jj] = *(const float4*)&sW[(v0 + jj)*68 + k4*4];
      #pragma unroll
      for (int kk = 0; kk < 4; kk++) {
        float4 x4 = *(const float4*)&sXC[(k4*4 + kk)*68 + tl0];
        #pragma unroll
        for (int jj = 0; jj < 4; jj++) {
          float w = kk==0 ? wv[jj].x : kk==1 ? wv[jj].y : kk==2 ? wv[jj].z : wv[jj].w;
          acc[0][jj] = fmaf(x4.x, w, acc[0][jj]);
          acc[1][jj] = fmaf(x4.y, w, acc[1][jj]);
          acc[2][jj] = fmaf(x4.z, w, acc[2][jj]);
          acc[3][jj] = fmaf(x4.w, w, acc[3][jj]);
        }
      }
    }

    const int j0g = pass*64 + v0;   // multiple of 4; region bounds 4,132,260 are too
    if (j0g < 4) {
      #pragma unroll
      for (int ti = 0; ti < 4; ti++)
        #pragma unroll
        for (int jj = 0; jj < 4; jj++)
          sDT[(tl0 + ti)*5 + jj] = acc[ti][jj];
    } else if (j0g < 132) {
      #pragma unroll
      for (int ti = 0; ti < 4; ti++)
        *(float4*)&BM[(r*256 + t0 + tl0 + ti)*128 + (j0g - 4)] =
            make_float4(acc[ti][0], acc[ti][1], acc[ti][2], acc[ti][3]);
    } else if (j0g < 260) {
      #pragma unroll
      for (int ti = 0; ti < 4; ti++)
        *(float4*)&CM[(r*256 + t0 + tl0 + ti)*128 + (j0g - 132)] =
            make_float4(acc[ti][0], acc[ti][1], acc[ti][2], acc[ti][3]);
    }
  }
  __syncthreads();

  for (int e = tid; e < 64*64; e += 256) {
    int t = e >> 6, d = e & 63;
    float4 w4 = *(const float4*)&dtw[d*4];
    float x = dtb[d];
    x = fmaf(sDT[t*5 + 0], w4.x, x);
    x = fmaf(sDT[t*5 + 1], w4.y, x);
    x = fmaf(sDT[t*5 + 2], w4.z, x);
    x = fmaf(sDT[t*5 + 3], w4.w, x);
    DELTA[(r*256 + t0 + t)*64 + d] = softplus_f(x);
  }
}

// ---------------------------------------------------------------------------
// K3: selective scan, R7: zero-LDS, zero-barrier, DPP reduce.
// grid 1024: bid -> r (128 rows) x sc (2 s-chunks of 64) x dc (4 d-chunks of 16).
// block 256: dg = tid>>4 (16 d's), sg = tid&15 (16 s-groups of 4 states).
// Thread owns 1 d x 4 s states in registers for all 256 timesteps.
// B/C read as per-lane float4 from global (16 lanes share lines -> L1 broadcast).
// 16-lane s-reduce via DPP row_ror rotate-adds (VALU, aligned to DPP rows).
// Writes YP[sc][r][t][d] partials (layout unchanged -> k4 unchanged).
// ---------------------------------------------------------------------------
__global__ __launch_bounds__(256) void k3_scan(
    const float* __restrict__ DELTA, const float* __restrict__ XC,
    const float* __restrict__ BM, const float* __restrict__ CM,
    const float* __restrict__ alog, float* __restrict__ YP)
{
  const int bid = blockIdx.x;
  const int r = bid & 127;
  const int rest = bid >> 7;
  const int sc = rest & 1;        // s-chunk: 64 states
  const int dc = rest >> 1;       // d-chunk: 16 channels
  const int tid = threadIdx.x;
  const int dg = tid >> 4;        // d within chunk
  const int sg = tid & 15;        // s-group (4 states each)
  const int sl0 = sg * 4;
  const int d = dc*16 + dg;
  const float LOG2E = 1.44269504f;

  float a2[4], h[4];
  #pragma unroll
  for (int j = 0; j < 4; j++) {
    a2[j] = -expf(alog[d*128 + sc*64 + sl0 + j]) * LOG2E;
    h[j] = 0.f;
  }

  const float* pB = BM    + r*256*128 + sc*64 + sl0;   // t-stride 128
  const float* pC = CM    + r*256*128 + sc*64 + sl0;
  const float* pD = DELTA + r*256*64  + d;             // t-stride 64
  const float* pX = XC    + r*256*64  + d;
  float*       pY = YP + ((size_t)(sc*128 + r))*256*64 + d;  // t-stride 64

  #pragma unroll 4
  for (int t = 0; t < 256; t++) {
    float4 Bv = *(const float4*)(pB + t*128);
    float4 Cv = *(const float4*)(pC + t*128);
    float dl = pD[t*64];
    float xv = pX[t*64];
    float u = dl * xv;
    float y;
    {
      float dA0 = exp2f(dl * a2[0]);
      h[0] = fmaf(dA0, h[0], u * Bv.x);
      y = h[0] * Cv.x;
      float dA1 = exp2f(dl * a2[1]);
      h[1] = fmaf(dA1, h[1], u * Bv.y);
      y = fmaf(h[1], Cv.y, y);
      float dA2 = exp2f(dl * a2[2]);
      h[2] = fmaf(dA2, h[2], u * Bv.z);
      y = fmaf(h[2], Cv.z, y);
      float dA3 = exp2f(dl * a2[3]);
      h[3] = fmaf(dA3, h[3], u * Bv.w);
      y = fmaf(h[3], Cv.w, y);
    }
    // 16-lane rotate-reduce on the VALU pipe (DPP row_ror 1,2,4,8).
    // Reduce groups (sg = tid&15) align exactly with DPP 16-lane rows.
    {
      int yi;
      yi = __builtin_amdgcn_update_dpp(__float_as_int(y), __float_as_int(y),
                                       0x121, 0xf, 0xf, false);   // row_ror:1
      y += __int_as_float(yi);
      yi = __builtin_amdgcn_update_dpp(__float_as_int(y), __float_as_int(y),
                                       0x122, 0xf, 0xf, false);   // row_ror:2
      y += __int_as_float(yi);
      yi = __builtin_amdgcn_update_dpp(__float_as_int(y), __float_as_int(y),
                                       0x124, 0xf, 0xf, false);   // row_ror:4
      y += __int_as_float(yi);
      yi = __builtin_amdgcn_update_dpp(__float_as_int(y), __float_as_int(y),
                                       0x128, 0xf, 0xf, false);   // row_ror:8
      y += __int_as_float(yi);
    }
    if (sg == 0)
      pY[t*64] = y;
  }
}

// ---------------------------------------------------------------------------
// K4: y=yp0+yp1 ; y2=y+xc*D ; y3=y2*silu(z) ; u=silu(y3@opw.T) ;
//     v=u@wout.T+bout -> d_out (pre-LN) + per-block stats
// grid 512 = 128 rows x 4 t-tiles(64), block 256
// ---------------------------------------------------------------------------
__global__ __launch_bounds__(256) void k4_post(
    const float* __restrict__ YP, const float* __restrict__ XC,
    const float* __restrict__ Zb, const float* __restrict__ Dp,
    const float* __restrict__ opw, const float* __restrict__ wout,
    const float* __restrict__ bout, float* __restrict__ out,
    float* __restrict__ PSTAT)
{
  __shared__ float sY[64*68];   // y3 transposed [d][t]
  __shared__ float sU[64*68];   // u transposed [e][t]
  __shared__ float sW[64*68];
  __shared__ float sRs[256], sRq[256];
  const int bid = blockIdx.x;
  const int r = bid >> 2, tb = bid & 3;
  const int b = r >> 5, node = r & 31;
  const int t0 = tb * 64;
  const int tid = threadIdx.x;
  const int tg = tid & 15, vg = tid >> 4;
  const int tl0 = tg * 4, v0 = vg * 4;

  for (int e = tid; e < 64*64; e += 256) {
    int t = e >> 6, d = e & 63;
    int idx = (r*256 + t0 + t)*64 + d;
    float y = YP[idx] + YP[2097152 + idx];
    float y2 = fmaf(XC[idx], Dp[d], y);
    sY[d*68 + t] = y2 * silu_f(Zb[idx]);
  }

  // Phase A: u[t][e'] = silu( sum_d y3[d][t] * opw[e'][d] )
  __syncthreads();
  for (int e = tid; e < 64*16; e += 256) {
    int row = e >> 4, c4 = e & 15;
    *(float4*)&sW[row*68 + c4*4] = *(const float4*)&opw[row*64 + c4*4];
  }
  __syncthreads();

  {
    float acc[4][4];
    #pragma unroll
    for (int ti = 0; ti < 4; ti++)
      #pragma unroll
      for (int j = 0; j < 4; j++) acc[ti][j] = 0.f;
    for (int k4 = 0; k4 < 16; k4++) {
      float4 wv[4];
      #pragma unroll
      for (int j = 0; j < 4; j++)
        wv[j] = *(const float4*)&sW[(v0 + j)*68 + k4*4];
      #pragma unroll
      for (int kk = 0; kk < 4; kk++) {
        float4 x4 = *(const float4*)&sY[(k4*4 + kk)*68 + tl0];
        #pragma unroll
        for (int j = 0; j < 4; j++) {
          float w = kk==0 ? wv[j].x : kk==1 ? wv[j].y : kk==2 ? wv[j].z : wv[j].w;
          acc[0][j] = fmaf(x4.x, w, acc[0][j]);
          acc[1][j] = fmaf(x4.y, w, acc[1][j]);
          acc[2][j] = fmaf(x4.z, w, acc[2][j]);
          acc[3][j] = fmaf(x4.w, w, acc[3][j]);
        }
      }
    }
    #pragma unroll
    for (int j = 0; j < 4; j++)
      *(float4*)&sU[(v0 + j)*68 + tl0] =
          make_float4(silu_f(acc[0][j]), silu_f(acc[1][j]),
                      silu_f(acc[2][j]), silu_f(acc[3][j]));
  }

  // Phase B: v[t][o] = bout[o] + sum_e u[e][t] * wout[o][e]  (o: 2 passes of 64)
  float s = 0.f, q = 0.f;
  for (int pass = 0; pass < 2; pass++) {
    __syncthreads();   // sU visible (pass0) / sW read-done
    for (int e = tid; e < 64*16; e += 256) {
      int row = e >> 4, c4 = e & 15;
      *(float4*)&sW[row*68 + c4*4] = *(const float4*)&wout[(pass*64 + row)*64 + c4*4];
    }
    __syncthreads();

    float a2[4][4];
    #pragma unroll
    for (int ti = 0; ti < 4; ti++)
      #pragma unroll
      for (int j = 0; j < 4; j++) a2[ti][j] = bout[pass*64 + v0 + j];

    for (int k4 = 0; k4 < 16; k4++) {
      float4 wv[4];
      #pragma unroll
      for (int j = 0; j < 4; j++)
        wv[j] = *(const float4*)&sW[(v0 + j)*68 + k4*4];
      #pragma unroll
      for (int kk = 0; kk < 4; kk++) {
        float4 x4 = *(const float4*)&sU[(k4*4 + kk)*68 + tl0];
        #pragma unroll
        for (int j = 0; j < 4; j++) {
          float w = kk==0 ? wv[j].x : kk==1 ? wv[j].y : kk==2 ? wv[j].z : wv[j].w;
          a2[0][j] = fmaf(x4.x, w, a2[0][j]);
          a2[1][j] = fmaf(x4.y, w, a2[1][j]);
          a2[2][j] = fmaf(x4.z, w, a2[2][j]);
          a2[3][j] = fmaf(x4.w, w, a2[3][j]);
        }
      }
    }

    #pragma unroll
    for (int ti = 0; ti < 4; ti++)
      #pragma unroll
      for (int j = 0; j < 4; j++) {
        float v = a2[ti][j];
        s += v;
        q = fmaf(v, v, q);
      }
    #pragma unroll
    for (int j = 0; j < 4; j++) {
      int o = pass*64 + v0 + j;
      *(float4*)&out[((b*128 + o)*32 + node)*256 + t0 + tl0] =
          make_float4(a2[0][j], a2[1][j], a2[2][j], a2[3][j]);
    }
  }

  sRs[tid] = s; sRq[tid] = q;
  __syncthreads();
  for (int st = 128; st > 0; st >>= 1) {
    if (tid < st) { sRs[tid] += sRs[tid + st]; sRq[tid] += sRq[tid + st]; }
    __syncthreads();
  }
  if (tid == 0) { PSTAT[bid*2] = sRs[0]; PSTAT[bid*2 + 1] = sRq[0]; }
}

// ---------------------------------------------------------------------------
// K5: LayerNorm in place on d_out (unchanged). grid 1024, block 256
// ---------------------------------------------------------------------------
__global__ __launch_bounds__(256) void k5_ln(
    const float* __restrict__ PSTAT, const float* __restrict__ lnw,
    const float* __restrict__ lnb, float* __restrict__ out)
{
  __shared__ float sLW[32*129], sLB[32*129];
  const int bid = blockIdx.x;
  const int r = bid >> 3, tb = bid & 7;
  const int b = r >> 5, node = r & 31;
  const int t0 = tb * 32;
  const int tid = threadIdx.x;

  float s = 0.f, q = 0.f;
  #pragma unroll
  for (int p = 0; p < 4; p++) {
    s += PSTAT[(r*4 + p)*2];
    q += PSTAT[(r*4 + p)*2 + 1];
  }
  const float mu = s * (1.f / 32768.f);
  const float var = q * (1.f / 32768.f) - mu * mu;
  const float rstd = rsqrtf(var + 1e-5f);

  for (int e = tid; e < 32*128; e += 256) {
    int t = e >> 7, o = e & 127;
    sLW[t*129 + o] = lnw[(t0 + t)*128 + o];
    sLB[t*129 + o] = lnb[(t0 + t)*128 + o];
  }
  __syncthreads();

  for (int n = 0; n < 16; n++) {
    int t = tid & 31;
    int o = (tid >> 5) + n*8;
    int idx = ((b*128 + o)*32 + node)*256 + t0 + t;
    float v = out[idx];
    out[idx] = fmaf((v - mu) * rstd, sLW[t*129 + o], sLB[t*129 + o]);
  }
}

// ---------------------------------------------------------------------------
extern "C" void kernel_launch(void* const* d_in, const int* in_sizes, int n_in,
                              void* d_out, int out_size, void* d_ws, size_t ws_size,
                              hipStream_t stream)
{
  (void)in_sizes; (void)n_in; (void)out_size; (void)ws_size;
  const float* inp   = (const float*)d_in[0];
  const float* w_in  = (const float*)d_in[1];
  const float* b_in  = (const float*)d_in[2];
  const float* ipw   = (const float*)d_in[3];
  const float* convw = (const float*)d_in[4];
  const float* convb = (const float*)d_in[5];
  const float* xpw   = (const float*)d_in[6];
  const float* dtw   = (const float*)d_in[7];
  const float* dtb   = (const float*)d_in[8];
  const float* alog  = (const float*)d_in[9];
  const float* Dp    = (const float*)d_in[10];
  const float* opw   = (const float*)d_in[11];
  const float* wout  = (const float*)d_in[12];
  const float* bout  = (const float*)d_in[13];
  const float* lnw   = (const float*)d_in[14];
  const float* lnb   = (const float*)d_in[15];

  float* ws = (float*)d_ws;
  float* XM    = ws + 0;
  float* Zb    = ws + 2097152;
  float* XC    = ws + 4194304;
  float* DELTA = ws + 6291456;
  float* BM    = ws + 8388608;
  float* CM    = ws + 12582912;
  float* YP    = ws + 16777216;   // 2 x 128 x 256 x 64
  float* PSTAT = ws + 20971520;   // 512 x 2
  float* out   = (float*)d_out;

  k1_proj<<<dim3(512), dim3(256), 0, stream>>>(inp, w_in, b_in, ipw, XM, Zb);
  k2_conv_xproj<<<dim3(512), dim3(256), 0, stream>>>(XM, convw, convb, xpw, dtw, dtb,
                                                     XC, DELTA, BM, CM);
  k3_scan<<<dim3(1024), dim3(256), 0, stream>>>(DELTA, XC, BM, CM, alog, YP);
  k4_post<<<dim3(512), dim3(256), 0, stream>>>(YP, XC, Zb, Dp, opw, wout, bout, out, PSTAT);
  k5_ln<<<dim3(1024), dim3(256), 0, stream>>>(PSTAT, lnw, lnb, out);
}

// Round 10
// 195.883 us; speedup vs baseline: 1.0842x; 1.0842x over previous
//
#include <hip/hip_runtime.h>
#include <math.h>

// Problem dims
// B=4, N_IN=128, NODE=32, L=256, N_HID=D_IN=64, D_STATE=128, DT_RANK=4, N_OUT=128
// R = B*NODE = 128 rows, each row independent; L sequential only in the scan (k3).
//
// R9 change: k3's exp2f() was libm-precise (OCML multi-instruction: ~112 VALU
// instr/t/wave measured via VALUBusy arithmetic vs ~34 expected). Replace with
// native v_exp_f32 via __builtin_amdgcn_exp2f (fallback __expf(x*ln2), also
// native). Everything else identical to R7.

__device__ __forceinline__ float silu_f(float v) { return v / (1.f + __expf(-v)); }
__device__ __forceinline__ float softplus_f(float v) { return v > 20.f ? v : log1pf(__expf(v)); }

#if __has_builtin(__builtin_amdgcn_exp2f)
#define EXP2N(x) __builtin_amdgcn_exp2f(x)
#else
#define EXP2N(x) __expf((x) * 0.6931471805599453f)   // 2^x = e^(x ln2), native
#endif

// ---------------------------------------------------------------------------
// K1: X = in @ w_in.T + b_in ; XZ = X @ in_proj_w.T -> XM (first 64), Z (last 64)
// grid 512 = 128 rows x 4 t-tiles(64), block 256
// ---------------------------------------------------------------------------
__global__ __launch_bounds__(256) void k1_proj(
    const float* __restrict__ inp, const float* __restrict__ w_in,
    const float* __restrict__ b_in, const float* __restrict__ ipw,
    float* __restrict__ XM, float* __restrict__ Zb)
{
  __shared__ float sIN[128*64];   // [i=128][t=64]
  __shared__ float sW[64*68];     // staged weight tile [row][k], stride 68
  __shared__ float sXT[64*68];    // X transposed [h][t], stride 68
  const int bid = blockIdx.x;
  const int r = bid >> 2, tb = bid & 3;
  const int b = r >> 5, node = r & 31;
  const int t0 = tb * 64;
  const int tid = threadIdx.x;
  const int tg = tid & 15, vg = tid >> 4;
  const int tl0 = tg * 4, v0 = vg * 4;

  for (int e = tid; e < 128*64; e += 256) {
    int i = e >> 6, t = e & 63;
    sIN[e] = inp[((b*128 + i)*32 + node)*256 + t0 + t];
  }

  // Phase A: X[t][h] = b_in[h] + sum_i in[i][t] * w_in[h][i]   (K=128, 2 chunks)
  float acc[4][4];
  #pragma unroll
  for (int ti = 0; ti < 4; ti++)
    #pragma unroll
    for (int j = 0; j < 4; j++) acc[ti][j] = b_in[v0 + j];

  for (int kc = 0; kc < 2; kc++) {
    __syncthreads();   // sIN ready (kc=0) / sW read-done (kc=1)
    for (int e = tid; e < 64*16; e += 256) {
      int row = e >> 4, c4 = e & 15;
      *(float4*)&sW[row*68 + c4*4] = *(const float4*)&w_in[row*128 + kc*64 + c4*4];
    }
    __syncthreads();
    for (int k4 = 0; k4 < 16; k4++) {
      float4 wv[4];
      #pragma unroll
      for (int j = 0; j < 4; j++)
        wv[j] = *(const float4*)&sW[(v0 + j)*68 + k4*4];
      #pragma unroll
      for (int kk = 0; kk < 4; kk++) {
        float4 x4 = *(const float4*)&sIN[(kc*64 + k4*4 + kk)*64 + tl0];
        #pragma unroll
        for (int j = 0; j < 4; j++) {
          float w = kk==0 ? wv[j].x : kk==1 ? wv[j].y : kk==2 ? wv[j].z : wv[j].w;
          acc[0][j] = fmaf(x4.x, w, acc[0][j]);
          acc[1][j] = fmaf(x4.y, w, acc[1][j]);
          acc[2][j] = fmaf(x4.z, w, acc[2][j]);
          acc[3][j] = fmaf(x4.w, w, acc[3][j]);
        }
      }
    }
  }
  // stash X^T into sXT[h][t]
  #pragma unroll
  for (int j = 0; j < 4; j++)
    *(float4*)&sXT[(v0 + j)*68 + tl0] =
        make_float4(acc[0][j], acc[1][j], acc[2][j], acc[3][j]);

  // Phase B: XZ[t][c] = sum_h X[h][t] * ipw[c][h]   (c: 2 passes of 64)
  for (int pass = 0; pass < 2; pass++) {
    __syncthreads();   // sXT visible (pass0) / sW read-done
    for (int e = tid; e < 64*16; e += 256) {
      int row = e >> 4, c4 = e & 15;
      *(float4*)&sW[row*68 + c4*4] = *(const float4*)&ipw[(pass*64 + row)*64 + c4*4];
    }
    __syncthreads();

    float a2[4][4];
    #pragma unroll
    for (int ti = 0; ti < 4; ti++)
      #pragma unroll
      for (int j = 0; j < 4; j++) a2[ti][j] = 0.f;

    for (int k4 = 0; k4 < 16; k4++) {
      float4 wv[4];
      #pragma unroll
      for (int j = 0; j < 4; j++)
        wv[j] = *(const float4*)&sW[(v0 + j)*68 + k4*4];
      #pragma unroll
      for (int kk = 0; kk < 4; kk++) {
        float4 x4 = *(const float4*)&sXT[(k4*4 + kk)*68 + tl0];
        #pragma unroll
        for (int j = 0; j < 4; j++) {
          float w = kk==0 ? wv[j].x : kk==1 ? wv[j].y : kk==2 ? wv[j].z : wv[j].w;
          a2[0][j] = fmaf(x4.x, w, a2[0][j]);
          a2[1][j] = fmaf(x4.y, w, a2[1][j]);
          a2[2][j] = fmaf(x4.z, w, a2[2][j]);
          a2[3][j] = fmaf(x4.w, w, a2[3][j]);
        }
      }
    }

    float* dst = (pass == 0) ? XM : Zb;
    #pragma unroll
    for (int ti = 0; ti < 4; ti++)
      *(float4*)&dst[(r*256 + t0 + tl0 + ti)*64 + v0] =
          make_float4(a2[ti][0], a2[ti][1], a2[ti][2], a2[ti][3]);
  }
}

// ---------------------------------------------------------------------------
// K2: conv+silu -> XC ; dbc = xc @ x_proj_w.T -> (dt | B | C) ; delta=softplus(...)
// grid 512 = 128 rows x 4 t-tiles(64), block 256
// ---------------------------------------------------------------------------
__global__ __launch_bounds__(256) void k2_conv_xproj(
    const float* __restrict__ XM, const float* __restrict__ convw,
    const float* __restrict__ convb, const float* __restrict__ xpw,
    const float* __restrict__ dtw, const float* __restrict__ dtb,
    float* __restrict__ XC, float* __restrict__ DELTA,
    float* __restrict__ BM, float* __restrict__ CM)
{
  __shared__ float sXM[65*64];    // [tt in -1..63][d]
  __shared__ float sXC[64*68];    // xc transposed [d][t], stride 68
  __shared__ float sW[64*68];     // staged x_proj_w tile
  __shared__ float sDT[64*5];     // dt[t][4], stride 5
  const int bid = blockIdx.x;
  const int r = bid >> 2, tb = bid & 3;
  const int t0 = tb * 64;
  const int tid = threadIdx.x;
  const int tg = tid & 15, vg = tid >> 4;
  const int tl0 = tg * 4, v0 = vg * 4;

  for (int e = tid; e < 65*64; e += 256) {
    int tt = e >> 6, d = e & 63;
    int tgl = t0 - 1 + tt;
    sXM[e] = (tgl < 0) ? 0.f : XM[(r*256 + tgl)*64 + d];
  }
  __syncthreads();

  for (int e = tid; e < 64*64; e += 256) {
    int t = e >> 6, d = e & 63;
    float c0 = convw[d*2], c1 = convw[d*2 + 1];
    float pre = fmaf(sXM[t*64 + d], c0, fmaf(sXM[(t+1)*64 + d], c1, convb[d]));
    float v = silu_f(pre);
    sXC[d*68 + t] = v;                       // transposed store
    XC[(r*256 + t0 + t)*64 + d] = v;         // coalesced global store
  }

  // dbc[t][j] = sum_d xc[d][t] * xpw[j][d],  j in 0..259 -> 5 passes of 64
  for (int pass = 0; pass < 5; pass++) {
    __syncthreads();   // sXC ready (pass0) / sW read-done
    for (int e = tid; e < 64*16; e += 256) {
      int row = e >> 4, c4 = e & 15;
      int grow = pass*64 + row;
      float4 w = (grow < 260) ? *(const float4*)&xpw[grow*64 + c4*4]
                              : make_float4(0.f, 0.f, 0.f, 0.f);
      *(float4*)&sW[row*68 + c4*4] = w;
    }
    __syncthreads();

    float acc[4][4];
    #pragma unroll
    for (int ti = 0; ti < 4; ti++)
      #pragma unroll
      for (int jj = 0; jj < 4; jj++) acc[ti][jj] = 0.f;

    for (int k4 = 0; k4 < 16; k4++) {
      float4 wv[4];
      #pragma unroll
      for (int jj = 0; jj < 4; jj++)
        wv[jj] = *(const float4*)&sW[(v0 + jj)*68 + k4*4];
      #pragma unroll
      for (int kk = 0; kk < 4; kk++) {
        float4 x4 = *(const float4*)&sXC[(k4*4 + kk)*68 + tl0];
        #pragma unroll
        for (int jj = 0; jj < 4; jj++) {
          float w = kk==0 ? wv[jj].x : kk==1 ? wv[jj].y : kk==2 ? wv[jj].z : wv[jj].w;
          acc[0][jj] = fmaf(x4.x, w, acc[0][jj]);
          acc[1][jj] = fmaf(x4.y, w, acc[1][jj]);
          acc[2][jj] = fmaf(x4.z, w, acc[2][jj]);
          acc[3][jj] = fmaf(x4.w, w, acc[3][jj]);
        }
      }
    }

    const int j0g = pass*64 + v0;   // multiple of 4; region bounds 4,132,260 are too
    if (j0g < 4) {
      #pragma unroll
      for (int ti = 0; ti < 4; ti++)
        #pragma unroll
        for (int jj = 0; jj < 4; jj++)
          sDT[(tl0 + ti)*5 + jj] = acc[ti][jj];
    } else if (j0g < 132) {
      #pragma unroll
      for (int ti = 0; ti < 4; ti++)
        *(float4*)&BM[(r*256 + t0 + tl0 + ti)*128 + (j0g - 4)] =
            make_float4(acc[ti][0], acc[ti][1], acc[ti][2], acc[ti][3]);
    } else if (j0g < 260) {
      #pragma unroll
      for (int ti = 0; ti < 4; ti++)
        *(float4*)&CM[(r*256 + t0 + tl0 + ti)*128 + (j0g - 132)] =
            make_float4(acc[ti][0], acc[ti][1], acc[ti][2], acc[ti][3]);
    }
  }
  __syncthreads();

  for (int e = tid; e < 64*64; e += 256) {
    int t = e >> 6, d = e & 63;
    float4 w4 = *(const float4*)&dtw[d*4];
    float x = dtb[d];
    x = fmaf(sDT[t*5 + 0], w4.x, x);
    x = fmaf(sDT[t*5 + 1], w4.y, x);
    x = fmaf(sDT[t*5 + 2], w4.z, x);
    x = fmaf(sDT[t*5 + 3], w4.w, x);
    DELTA[(r*256 + t0 + t)*64 + d] = softplus_f(x);
  }
}

// ---------------------------------------------------------------------------
// K3: selective scan: zero-LDS, zero-barrier, DPP reduce, native exp2.
// grid 1024: bid -> r (128 rows) x sc (2 s-chunks of 64) x dc (4 d-chunks of 16).
// block 256: dg = tid>>4 (16 d's), sg = tid&15 (16 s-groups of 4 states).
// ---------------------------------------------------------------------------
__global__ __launch_bounds__(256) void k3_scan(
    const float* __restrict__ DELTA, const float* __restrict__ XC,
    const float* __restrict__ BM, const float* __restrict__ CM,
    const float* __restrict__ alog, float* __restrict__ YP)
{
  const int bid = blockIdx.x;
  const int r = bid & 127;
  const int rest = bid >> 7;
  const int sc = rest & 1;        // s-chunk: 64 states
  const int dc = rest >> 1;       // d-chunk: 16 channels
  const int tid = threadIdx.x;
  const int dg = tid >> 4;        // d within chunk
  const int sg = tid & 15;        // s-group (4 states each)
  const int sl0 = sg * 4;
  const int d = dc*16 + dg;
  const float LOG2E = 1.44269504f;

  float a2[4], h[4];
  #pragma unroll
  for (int j = 0; j < 4; j++) {
    a2[j] = -expf(alog[d*128 + sc*64 + sl0 + j]) * LOG2E;
    h[j] = 0.f;
  }

  const float* pB = BM    + r*256*128 + sc*64 + sl0;   // t-stride 128
  const float* pC = CM    + r*256*128 + sc*64 + sl0;
  const float* pD = DELTA + r*256*64  + d;             // t-stride 64
  const float* pX = XC    + r*256*64  + d;
  float*       pY = YP + ((size_t)(sc*128 + r))*256*64 + d;  // t-stride 64

  #pragma unroll 4
  for (int t = 0; t < 256; t++) {
    float4 Bv = *(const float4*)(pB + t*128);
    float4 Cv = *(const float4*)(pC + t*128);
    float dl = pD[t*64];
    float xv = pX[t*64];
    float u = dl * xv;
    float y;
    {
      float dA0 = EXP2N(dl * a2[0]);
      h[0] = fmaf(dA0, h[0], u * Bv.x);
      y = h[0] * Cv.x;
      float dA1 = EXP2N(dl * a2[1]);
      h[1] = fmaf(dA1, h[1], u * Bv.y);
      y = fmaf(h[1], Cv.y, y);
      float dA2 = EXP2N(dl * a2[2]);
      h[2] = fmaf(dA2, h[2], u * Bv.z);
      y = fmaf(h[2], Cv.z, y);
      float dA3 = EXP2N(dl * a2[3]);
      h[3] = fmaf(dA3, h[3], u * Bv.w);
      y = fmaf(h[3], Cv.w, y);
    }
    // 16-lane rotate-reduce on the VALU pipe (DPP row_ror 1,2,4,8).
    {
      int yi;
      yi = __builtin_amdgcn_update_dpp(__float_as_int(y), __float_as_int(y),
                                       0x121, 0xf, 0xf, false);   // row_ror:1
      y += __int_as_float(yi);
      yi = __builtin_amdgcn_update_dpp(__float_as_int(y), __float_as_int(y),
                                       0x122, 0xf, 0xf, false);   // row_ror:2
      y += __int_as_float(yi);
      yi = __builtin_amdgcn_update_dpp(__float_as_int(y), __float_as_int(y),
                                       0x124, 0xf, 0xf, false);   // row_ror:4
      y += __int_as_float(yi);
      yi = __builtin_amdgcn_update_dpp(__float_as_int(y), __float_as_int(y),
                                       0x128, 0xf, 0xf, false);   // row_ror:8
      y += __int_as_float(yi);
    }
    if (sg == 0)
      pY[t*64] = y;
  }
}

// ---------------------------------------------------------------------------
// K4: y=yp0+yp1 ; y2=y+xc*D ; y3=y2*silu(z) ; u=silu(y3@opw.T) ;
//     v=u@wout.T+bout -> d_out (pre-LN) + per-block stats
// grid 512 = 128 rows x 4 t-tiles(64), block 256
// ---------------------------------------------------------------------------
__global__ __launch_bounds__(256) void k4_post(
    const float* __restrict__ YP, const float* __restrict__ XC,
    const float* __restrict__ Zb, const float* __restrict__ Dp,
    const float* __restrict__ opw, const float* __restrict__ wout,
    const float* __restrict__ bout, float* __restrict__ out,
    float* __restrict__ PSTAT)
{
  __shared__ float sY[64*68];   // y3 transposed [d][t]
  __shared__ float sU[64*68];   // u transposed [e][t]
  __shared__ float sW[64*68];
  __shared__ float sRs[256], sRq[256];
  const int bid = blockIdx.x;
  const int r = bid >> 2, tb = bid & 3;
  const int b = r >> 5, node = r & 31;
  const int t0 = tb * 64;
  const int tid = threadIdx.x;
  const int tg = tid & 15, vg = tid >> 4;
  const int tl0 = tg * 4, v0 = vg * 4;

  for (int e = tid; e < 64*64; e += 256) {
    int t = e >> 6, d = e & 63;
    int idx = (r*256 + t0 + t)*64 + d;
    float y = YP[idx] + YP[2097152 + idx];
    float y2 = fmaf(XC[idx], Dp[d], y);
    sY[d*68 + t] = y2 * silu_f(Zb[idx]);
  }

  // Phase A: u[t][e'] = silu( sum_d y3[d][t] * opw[e'][d] )
  __syncthreads();
  for (int e = tid; e < 64*16; e += 256) {
    int row = e >> 4, c4 = e & 15;
    *(float4*)&sW[row*68 + c4*4] = *(const float4*)&opw[row*64 + c4*4];
  }
  __syncthreads();

  {
    float acc[4][4];
    #pragma unroll
    for (int ti = 0; ti < 4; ti++)
      #pragma unroll
      for (int j = 0; j < 4; j++) acc[ti][j] = 0.f;
    for (int k4 = 0; k4 < 16; k4++) {
      float4 wv[4];
      #pragma unroll
      for (int j = 0; j < 4; j++)
        wv[j] = *(const float4*)&sW[(v0 + j)*68 + k4*4];
      #pragma unroll
      for (int kk = 0; kk < 4; kk++) {
        float4 x4 = *(const float4*)&sY[(k4*4 + kk)*68 + tl0];
        #pragma unroll
        for (int j = 0; j < 4; j++) {
          float w = kk==0 ? wv[j].x : kk==1 ? wv[j].y : kk==2 ? wv[j].z : wv[j].w;
          acc[0][j] = fmaf(x4.x, w, acc[0][j]);
          acc[1][j] = fmaf(x4.y, w, acc[1][j]);
          acc[2][j] = fmaf(x4.z, w, acc[2][j]);
          acc[3][j] = fmaf(x4.w, w, acc[3][j]);
        }
      }
    }
    #pragma unroll
    for (int j = 0; j < 4; j++)
      *(float4*)&sU[(v0 + j)*68 + tl0] =
          make_float4(silu_f(acc[0][j]), silu_f(acc[1][j]),
                      silu_f(acc[2][j]), silu_f(acc[3][j]));
  }

  // Phase B: v[t][o] = bout[o] + sum_e u[e][t] * wout[o][e]  (o: 2 passes of 64)
  float s = 0.f, q = 0.f;
  for (int pass = 0; pass < 2; pass++) {
    __syncthreads();   // sU visible (pass0) / sW read-done
    for (int e = tid; e < 64*16; e += 256) {
      int row = e >> 4, c4 = e & 15;
      *(float4*)&sW[row*68 + c4*4] = *(const float4*)&wout[(pass*64 + row)*64 + c4*4];
    }
    __syncthreads();

    float a2[4][4];
    #pragma unroll
    for (int ti = 0; ti < 4; ti++)
      #pragma unroll
      for (int j = 0; j < 4; j++) a2[ti][j] = bout[pass*64 + v0 + j];

    for (int k4 = 0; k4 < 16; k4++) {
      float4 wv[4];
      #pragma unroll
      for (int j = 0; j < 4; j++)
        wv[j] = *(const float4*)&sW[(v0 + j)*68 + k4*4];
      #pragma unroll
      for (int kk = 0; kk < 4; kk++) {
        float4 x4 = *(const float4*)&sU[(k4*4 + kk)*68 + tl0];
        #pragma unroll
        for (int j = 0; j < 4; j++) {
          float w = kk==0 ? wv[j].x : kk==1 ? wv[j].y : kk==2 ? wv[j].z : wv[j].w;
          a2[0][j] = fmaf(x4.x, w, a2[0][j]);
          a2[1][j] = fmaf(x4.y, w, a2[1][j]);
          a2[2][j] = fmaf(x4.z, w, a2[2][j]);
          a2[3][j] = fmaf(x4.w, w, a2[3][j]);
        }
      }
    }

    #pragma unroll
    for (int ti = 0; ti < 4; ti++)
      #pragma unroll
      for (int j = 0; j < 4; j++) {
        float v = a2[ti][j];
        s += v;
        q = fmaf(v, v, q);
      }
    #pragma unroll
    for (int j = 0; j < 4; j++) {
      int o = pass*64 + v0 + j;
      *(float4*)&out[((b*128 + o)*32 + node)*256 + t0 + tl0] =
          make_float4(a2[0][j], a2[1][j], a2[2][j], a2[3][j]);
    }
  }

  sRs[tid] = s; sRq[tid] = q;
  __syncthreads();
  for (int st = 128; st > 0; st >>= 1) {
    if (tid < st) { sRs[tid] += sRs[tid + st]; sRq[tid] += sRq[tid + st]; }
    __syncthreads();
  }
  if (tid == 0) { PSTAT[bid*2] = sRs[0]; PSTAT[bid*2 + 1] = sRq[0]; }
}

// ---------------------------------------------------------------------------
// K5: LayerNorm in place on d_out (unchanged). grid 1024, block 256
// ---------------------------------------------------------------------------
__global__ __launch_bounds__(256) void k5_ln(
    const float* __restrict__ PSTAT, const float* __restrict__ lnw,
    const float* __restrict__ lnb, float* __restrict__ out)
{
  __shared__ float sLW[32*129], sLB[32*129];
  const int bid = blockIdx.x;
  const int r = bid >> 3, tb = bid & 7;
  const int b = r >> 5, node = r & 31;
  const int t0 = tb * 32;
  const int tid = threadIdx.x;

  float s = 0.f, q = 0.f;
  #pragma unroll
  for (int p = 0; p < 4; p++) {
    s += PSTAT[(r*4 + p)*2];
    q += PSTAT[(r*4 + p)*2 + 1];
  }
  const float mu = s * (1.f / 32768.f);
  const float var = q * (1.f / 32768.f) - mu * mu;
  const float rstd = rsqrtf(var + 1e-5f);

  for (int e = tid; e < 32*128; e += 256) {
    int t = e >> 7, o = e & 127;
    sLW[t*129 + o] = lnw[(t0 + t)*128 + o];
    sLB[t*129 + o] = lnb[(t0 + t)*128 + o];
  }
  __syncthreads();

  for (int n = 0; n < 16; n++) {
    int t = tid & 31;
    int o = (tid >> 5) + n*8;
    int idx = ((b*128 + o)*32 + node)*256 + t0 + t;
    float v = out[idx];
    out[idx] = fmaf((v - mu) * rstd, sLW[t*129 + o], sLB[t*129 + o]);
  }
}

// ---------------------------------------------------------------------------
extern "C" void kernel_launch(void* const* d_in, const int* in_sizes, int n_in,
                              void* d_out, int out_size, void* d_ws, size_t ws_size,
                              hipStream_t stream)
{
  (void)in_sizes; (void)n_in; (void)out_size; (void)ws_size;
  const float* inp   = (const float*)d_in[0];
  const float* w_in  = (const float*)d_in[1];
  const float* b_in  = (const float*)d_in[2];
  const float* ipw   = (const float*)d_in[3];
  const float* convw = (const float*)d_in[4];
  const float* convb = (const float*)d_in[5];
  const float* xpw   = (const float*)d_in[6];
  const float* dtw   = (const float*)d_in[7];
  const float* dtb   = (const float*)d_in[8];
  const float* alog  = (const float*)d_in[9];
  const float* Dp    = (const float*)d_in[10];
  const float* opw   = (const float*)d_in[11];
  const float* wout  = (const float*)d_in[12];
  const float* bout  = (const float*)d_in[13];
  const float* lnw   = (const float*)d_in[14];
  const float* lnb   = (const float*)d_in[15];

  float* ws = (float*)d_ws;
  float* XM    = ws + 0;
  float* Zb    = ws + 2097152;
  float* XC    = ws + 4194304;
  float* DELTA = ws + 6291456;
  float* BM    = ws + 8388608;
  float* CM    = ws + 12582912;
  float* YP    = ws + 16777216;   // 2 x 128 x 256 x 64
  float* PSTAT = ws + 20971520;   // 512 x 2
  float* out   = (float*)d_out;

  k1_proj<<<dim3(512), dim3(256), 0, stream>>>(inp, w_in, b_in, ipw, XM, Zb);
  k2_conv_xproj<<<dim3(512), dim3(256), 0, stream>>>(XM, convw, convb, xpw, dtw, dtb,
                                                     XC, DELTA, BM, CM);
  k3_scan<<<dim3(1024), dim3(256), 0, stream>>>(DELTA, XC, BM, CM, alog, YP);
  k4_post<<<dim3(512), dim3(256), 0, stream>>>(YP, XC, Zb, Dp, opw, wout, bout, out, PSTAT);
  k5_ln<<<dim3(1024), dim3(256), 0, stream>>>(PSTAT, lnw, lnb, out);
}

// Round 11
// 185.837 us; speedup vs baseline: 1.1428x; 1.0541x over previous
//
#include <hip/hip_runtime.h>
#include <math.h>

// Problem dims
// B=4, N_IN=128, NODE=32, L=256, N_HID=D_IN=64, D_STATE=128, DT_RANK=4, N_OUT=128
// R = B*NODE = 128 rows, each row independent; L sequential only in the scan (k3).
//
// R10 change: k3 explicit depth-4 register software pipeline. R9 measured
// 105us, VALUBusy 58%, occ 42%: neither pipe saturated -> latency-bound
// (compiler unroll-4 issues loads right before use -> vmcnt stall every 4 t).
// Now: 4 NAMED register load-sets (A/B/C/D, no runtime indexing -> no scratch),
// prefetch distance 4 timesteps (~360 cyc compute cover vs ~200 cyc L2).
// k1/k2/k4/k5 unchanged.

__device__ __forceinline__ float silu_f(float v) { return v / (1.f + __expf(-v)); }
__device__ __forceinline__ float softplus_f(float v) { return v > 20.f ? v : log1pf(__expf(v)); }

#if __has_builtin(__builtin_amdgcn_exp2f)
#define EXP2N(x) __builtin_amdgcn_exp2f(x)
#else
#define EXP2N(x) __expf((x) * 0.6931471805599453f)   // 2^x = e^(x ln2), native
#endif

// ---------------------------------------------------------------------------
// K1: X = in @ w_in.T + b_in ; XZ = X @ in_proj_w.T -> XM (first 64), Z (last 64)
// grid 512 = 128 rows x 4 t-tiles(64), block 256
// ---------------------------------------------------------------------------
__global__ __launch_bounds__(256) void k1_proj(
    const float* __restrict__ inp, const float* __restrict__ w_in,
    const float* __restrict__ b_in, const float* __restrict__ ipw,
    float* __restrict__ XM, float* __restrict__ Zb)
{
  __shared__ float sIN[128*64];   // [i=128][t=64]
  __shared__ float sW[64*68];     // staged weight tile [row][k], stride 68
  __shared__ float sXT[64*68];    // X transposed [h][t], stride 68
  const int bid = blockIdx.x;
  const int r = bid >> 2, tb = bid & 3;
  const int b = r >> 5, node = r & 31;
  const int t0 = tb * 64;
  const int tid = threadIdx.x;
  const int tg = tid & 15, vg = tid >> 4;
  const int tl0 = tg * 4, v0 = vg * 4;

  for (int e = tid; e < 128*64; e += 256) {
    int i = e >> 6, t = e & 63;
    sIN[e] = inp[((b*128 + i)*32 + node)*256 + t0 + t];
  }

  // Phase A: X[t][h] = b_in[h] + sum_i in[i][t] * w_in[h][i]   (K=128, 2 chunks)
  float acc[4][4];
  #pragma unroll
  for (int ti = 0; ti < 4; ti++)
    #pragma unroll
    for (int j = 0; j < 4; j++) acc[ti][j] = b_in[v0 + j];

  for (int kc = 0; kc < 2; kc++) {
    __syncthreads();   // sIN ready (kc=0) / sW read-done (kc=1)
    for (int e = tid; e < 64*16; e += 256) {
      int row = e >> 4, c4 = e & 15;
      *(float4*)&sW[row*68 + c4*4] = *(const float4*)&w_in[row*128 + kc*64 + c4*4];
    }
    __syncthreads();
    for (int k4 = 0; k4 < 16; k4++) {
      float4 wv[4];
      #pragma unroll
      for (int j = 0; j < 4; j++)
        wv[j] = *(const float4*)&sW[(v0 + j)*68 + k4*4];
      #pragma unroll
      for (int kk = 0; kk < 4; kk++) {
        float4 x4 = *(const float4*)&sIN[(kc*64 + k4*4 + kk)*64 + tl0];
        #pragma unroll
        for (int j = 0; j < 4; j++) {
          float w = kk==0 ? wv[j].x : kk==1 ? wv[j].y : kk==2 ? wv[j].z : wv[j].w;
          acc[0][j] = fmaf(x4.x, w, acc[0][j]);
          acc[1][j] = fmaf(x4.y, w, acc[1][j]);
          acc[2][j] = fmaf(x4.z, w, acc[2][j]);
          acc[3][j] = fmaf(x4.w, w, acc[3][j]);
        }
      }
    }
  }
  // stash X^T into sXT[h][t]
  #pragma unroll
  for (int j = 0; j < 4; j++)
    *(float4*)&sXT[(v0 + j)*68 + tl0] =
        make_float4(acc[0][j], acc[1][j], acc[2][j], acc[3][j]);

  // Phase B: XZ[t][c] = sum_h X[h][t] * ipw[c][h]   (c: 2 passes of 64)
  for (int pass = 0; pass < 2; pass++) {
    __syncthreads();   // sXT visible (pass0) / sW read-done
    for (int e = tid; e < 64*16; e += 256) {
      int row = e >> 4, c4 = e & 15;
      *(float4*)&sW[row*68 + c4*4] = *(const float4*)&ipw[(pass*64 + row)*64 + c4*4];
    }
    __syncthreads();

    float a2[4][4];
    #pragma unroll
    for (int ti = 0; ti < 4; ti++)
      #pragma unroll
      for (int j = 0; j < 4; j++) a2[ti][j] = 0.f;

    for (int k4 = 0; k4 < 16; k4++) {
      float4 wv[4];
      #pragma unroll
      for (int j = 0; j < 4; j++)
        wv[j] = *(const float4*)&sW[(v0 + j)*68 + k4*4];
      #pragma unroll
      for (int kk = 0; kk < 4; kk++) {
        float4 x4 = *(const float4*)&sXT[(k4*4 + kk)*68 + tl0];
        #pragma unroll
        for (int j = 0; j < 4; j++) {
          float w = kk==0 ? wv[j].x : kk==1 ? wv[j].y : kk==2 ? wv[j].z : wv[j].w;
          a2[0][j] = fmaf(x4.x, w, a2[0][j]);
          a2[1][j] = fmaf(x4.y, w, a2[1][j]);
          a2[2][j] = fmaf(x4.z, w, a2[2][j]);
          a2[3][j] = fmaf(x4.w, w, a2[3][j]);
        }
      }
    }

    float* dst = (pass == 0) ? XM : Zb;
    #pragma unroll
    for (int ti = 0; ti < 4; ti++)
      *(float4*)&dst[(r*256 + t0 + tl0 + ti)*64 + v0] =
          make_float4(a2[ti][0], a2[ti][1], a2[ti][2], a2[ti][3]);
  }
}

// ---------------------------------------------------------------------------
// K2: conv+silu -> XC ; dbc = xc @ x_proj_w.T -> (dt | B | C) ; delta=softplus(...)
// grid 512 = 128 rows x 4 t-tiles(64), block 256
// ---------------------------------------------------------------------------
__global__ __launch_bounds__(256) void k2_conv_xproj(
    const float* __restrict__ XM, const float* __restrict__ convw,
    const float* __restrict__ convb, const float* __restrict__ xpw,
    const float* __restrict__ dtw, const float* __restrict__ dtb,
    float* __restrict__ XC, float* __restrict__ DELTA,
    float* __restrict__ BM, float* __restrict__ CM)
{
  __shared__ float sXM[65*64];    // [tt in -1..63][d]
  __shared__ float sXC[64*68];    // xc transposed [d][t], stride 68
  __shared__ float sW[64*68];     // staged x_proj_w tile
  __shared__ float sDT[64*5];     // dt[t][4], stride 5
  const int bid = blockIdx.x;
  const int r = bid >> 2, tb = bid & 3;
  const int t0 = tb * 64;
  const int tid = threadIdx.x;
  const int tg = tid & 15, vg = tid >> 4;
  const int tl0 = tg * 4, v0 = vg * 4;

  for (int e = tid; e < 65*64; e += 256) {
    int tt = e >> 6, d = e & 63;
    int tgl = t0 - 1 + tt;
    sXM[e] = (tgl < 0) ? 0.f : XM[(r*256 + tgl)*64 + d];
  }
  __syncthreads();

  for (int e = tid; e < 64*64; e += 256) {
    int t = e >> 6, d = e & 63;
    float c0 = convw[d*2], c1 = convw[d*2 + 1];
    float pre = fmaf(sXM[t*64 + d], c0, fmaf(sXM[(t+1)*64 + d], c1, convb[d]));
    float v = silu_f(pre);
    sXC[d*68 + t] = v;                       // transposed store
    XC[(r*256 + t0 + t)*64 + d] = v;         // coalesced global store
  }

  // dbc[t][j] = sum_d xc[d][t] * xpw[j][d],  j in 0..259 -> 5 passes of 64
  for (int pass = 0; pass < 5; pass++) {
    __syncthreads();   // sXC ready (pass0) / sW read-done
    for (int e = tid; e < 64*16; e += 256) {
      int row = e >> 4, c4 = e & 15;
      int grow = pass*64 + row;
      float4 w = (grow < 260) ? *(const float4*)&xpw[grow*64 + c4*4]
                              : make_float4(0.f, 0.f, 0.f, 0.f);
      *(float4*)&sW[row*68 + c4*4] = w;
    }
    __syncthreads();

    float acc[4][4];
    #pragma unroll
    for (int ti = 0; ti < 4; ti++)
      #pragma unroll
      for (int jj = 0; jj < 4; jj++) acc[ti][jj] = 0.f;

    for (int k4 = 0; k4 < 16; k4++) {
      float4 wv[4];
      #pragma unroll
      for (int jj = 0; jj < 4; jj++)
        wv[jj] = *(const float4*)&sW[(v0 + jj)*68 + k4*4];
      #pragma unroll
      for (int kk = 0; kk < 4; kk++) {
        float4 x4 = *(const float4*)&sXC[(k4*4 + kk)*68 + tl0];
        #pragma unroll
        for (int jj = 0; jj < 4; jj++) {
          float w = kk==0 ? wv[jj].x : kk==1 ? wv[jj].y : kk==2 ? wv[jj].z : wv[jj].w;
          acc[0][jj] = fmaf(x4.x, w, acc[0][jj]);
          acc[1][jj] = fmaf(x4.y, w, acc[1][jj]);
          acc[2][jj] = fmaf(x4.z, w, acc[2][jj]);
          acc[3][jj] = fmaf(x4.w, w, acc[3][jj]);
        }
      }
    }

    const int j0g = pass*64 + v0;   // multiple of 4; region bounds 4,132,260 are too
    if (j0g < 4) {
      #pragma unroll
      for (int ti = 0; ti < 4; ti++)
        #pragma unroll
        for (int jj = 0; jj < 4; jj++)
          sDT[(tl0 + ti)*5 + jj] = acc[ti][jj];
    } else if (j0g < 132) {
      #pragma unroll
      for (int ti = 0; ti < 4; ti++)
        *(float4*)&BM[(r*256 + t0 + tl0 + ti)*128 + (j0g - 4)] =
            make_float4(acc[ti][0], acc[ti][1], acc[ti][2], acc[ti][3]);
    } else if (j0g < 260) {
      #pragma unroll
      for (int ti = 0; ti < 4; ti++)
        *(float4*)&CM[(r*256 + t0 + tl0 + ti)*128 + (j0g - 132)] =
            make_float4(acc[ti][0], acc[ti][1], acc[ti][2], acc[ti][3]);
    }
  }
  __syncthreads();

  for (int e = tid; e < 64*64; e += 256) {
    int t = e >> 6, d = e & 63;
    float4 w4 = *(const float4*)&dtw[d*4];
    float x = dtb[d];
    x = fmaf(sDT[t*5 + 0], w4.x, x);
    x = fmaf(sDT[t*5 + 1], w4.y, x);
    x = fmaf(sDT[t*5 + 2], w4.z, x);
    x = fmaf(sDT[t*5 + 3], w4.w, x);
    DELTA[(r*256 + t0 + t)*64 + d] = softplus_f(x);
  }
}

// ---------------------------------------------------------------------------
// K3: selective scan: zero-LDS, zero-barrier, DPP reduce, native exp2,
// depth-4 register software pipeline (named sets A/B/C/D, prefetch dist 4).
// grid 1024: bid -> r (128 rows) x sc (2 s-chunks of 64) x dc (4 d-chunks of 16).
// block 256: dg = tid>>4 (16 d's), sg = tid&15 (16 s-groups of 4 states).
// ---------------------------------------------------------------------------
__global__ __launch_bounds__(256) void k3_scan(
    const float* __restrict__ DELTA, const float* __restrict__ XC,
    const float* __restrict__ BM, const float* __restrict__ CM,
    const float* __restrict__ alog, float* __restrict__ YP)
{
  const int bid = blockIdx.x;
  const int r = bid & 127;
  const int rest = bid >> 7;
  const int sc = rest & 1;        // s-chunk: 64 states
  const int dc = rest >> 1;       // d-chunk: 16 channels
  const int tid = threadIdx.x;
  const int dg = tid >> 4;        // d within chunk
  const int sg = tid & 15;        // s-group (4 states each)
  const int sl0 = sg * 4;
  const int d = dc*16 + dg;
  const float LOG2E = 1.44269504f;

  float a2[4], h[4];
  #pragma unroll
  for (int j = 0; j < 4; j++) {
    a2[j] = -expf(alog[d*128 + sc*64 + sl0 + j]) * LOG2E;
    h[j] = 0.f;
  }

  const float* pB = BM    + r*256*128 + sc*64 + sl0;   // t-stride 128
  const float* pC = CM    + r*256*128 + sc*64 + sl0;
  const float* pD = DELTA + r*256*64  + d;             // t-stride 64
  const float* pX = XC    + r*256*64  + d;
  float*       pY = YP + ((size_t)(sc*128 + r))*256*64 + d;  // t-stride 64

  // depth-4 pipeline registers (named sets -> stay in VGPRs, rule #20)
  float4 vB0, vC0, vB1, vC1, vB2, vC2, vB3, vC3;
  float  vD0, vX0, vD1, vX1, vD2, vX2, vD3, vX3;

#define K3_LD(SET, T_) do { \
    vB##SET = *(const float4*)(pB + (T_)*128); \
    vC##SET = *(const float4*)(pC + (T_)*128); \
    vD##SET = pD[(T_)*64]; \
    vX##SET = pX[(T_)*64]; \
  } while (0)

#define K3_STEP(SET, T_) do { \
    float dl = vD##SET, xv = vX##SET; \
    float4 Bv = vB##SET, Cv = vC##SET; \
    float u = dl * xv; \
    float y; \
    float dA0 = EXP2N(dl * a2[0]); \
    h[0] = fmaf(dA0, h[0], u * Bv.x); \
    y = h[0] * Cv.x; \
    float dA1 = EXP2N(dl * a2[1]); \
    h[1] = fmaf(dA1, h[1], u * Bv.y); \
    y = fmaf(h[1], Cv.y, y); \
    float dA2 = EXP2N(dl * a2[2]); \
    h[2] = fmaf(dA2, h[2], u * Bv.z); \
    y = fmaf(h[2], Cv.z, y); \
    float dA3 = EXP2N(dl * a2[3]); \
    h[3] = fmaf(dA3, h[3], u * Bv.w); \
    y = fmaf(h[3], Cv.w, y); \
    int yi; \
    yi = __builtin_amdgcn_update_dpp(__float_as_int(y), __float_as_int(y), \
                                     0x121, 0xf, 0xf, false); \
    y += __int_as_float(yi); \
    yi = __builtin_amdgcn_update_dpp(__float_as_int(y), __float_as_int(y), \
                                     0x122, 0xf, 0xf, false); \
    y += __int_as_float(yi); \
    yi = __builtin_amdgcn_update_dpp(__float_as_int(y), __float_as_int(y), \
                                     0x124, 0xf, 0xf, false); \
    y += __int_as_float(yi); \
    yi = __builtin_amdgcn_update_dpp(__float_as_int(y), __float_as_int(y), \
                                     0x128, 0xf, 0xf, false); \
    y += __int_as_float(yi); \
    if (sg == 0) pY[(T_)*64] = y; \
  } while (0)

  K3_LD(0, 0); K3_LD(1, 1); K3_LD(2, 2); K3_LD(3, 3);

  // main loop: consume t..t+3, prefetch t+4..t+7 (prefetch distance 4)
  for (int t = 0; t < 252; t += 4) {
    K3_STEP(0, t);     K3_LD(0, t + 4);
    K3_STEP(1, t + 1); K3_LD(1, t + 5);
    K3_STEP(2, t + 2); K3_LD(2, t + 6);
    K3_STEP(3, t + 3); K3_LD(3, t + 7);
  }
  // tail: t = 252..255, no prefetch
  K3_STEP(0, 252);
  K3_STEP(1, 253);
  K3_STEP(2, 254);
  K3_STEP(3, 255);

#undef K3_LD
#undef K3_STEP
}

// ---------------------------------------------------------------------------
// K4: y=yp0+yp1 ; y2=y+xc*D ; y3=y2*silu(z) ; u=silu(y3@opw.T) ;
//     v=u@wout.T+bout -> d_out (pre-LN) + per-block stats
// grid 512 = 128 rows x 4 t-tiles(64), block 256
// ---------------------------------------------------------------------------
__global__ __launch_bounds__(256) void k4_post(
    const float* __restrict__ YP, const float* __restrict__ XC,
    const float* __restrict__ Zb, const float* __restrict__ Dp,
    const float* __restrict__ opw, const float* __restrict__ wout,
    const float* __restrict__ bout, float* __restrict__ out,
    float* __restrict__ PSTAT)
{
  __shared__ float sY[64*68];   // y3 transposed [d][t]
  __shared__ float sU[64*68];   // u transposed [e][t]
  __shared__ float sW[64*68];
  __shared__ float sRs[256], sRq[256];
  const int bid = blockIdx.x;
  const int r = bid >> 2, tb = bid & 3;
  const int b = r >> 5, node = r & 31;
  const int t0 = tb * 64;
  const int tid = threadIdx.x;
  const int tg = tid & 15, vg = tid >> 4;
  const int tl0 = tg * 4, v0 = vg * 4;

  for (int e = tid; e < 64*64; e += 256) {
    int t = e >> 6, d = e & 63;
    int idx = (r*256 + t0 + t)*64 + d;
    float y = YP[idx] + YP[2097152 + idx];
    float y2 = fmaf(XC[idx], Dp[d], y);
    sY[d*68 + t] = y2 * silu_f(Zb[idx]);
  }

  // Phase A: u[t][e'] = silu( sum_d y3[d][t] * opw[e'][d] )
  __syncthreads();
  for (int e = tid; e < 64*16; e += 256) {
    int row = e >> 4, c4 = e & 15;
    *(float4*)&sW[row*68 + c4*4] = *(const float4*)&opw[row*64 + c4*4];
  }
  __syncthreads();

  {
    float acc[4][4];
    #pragma unroll
    for (int ti = 0; ti < 4; ti++)
      #pragma unroll
      for (int j = 0; j < 4; j++) acc[ti][j] = 0.f;
    for (int k4 = 0; k4 < 16; k4++) {
      float4 wv[4];
      #pragma unroll
      for (int j = 0; j < 4; j++)
        wv[j] = *(const float4*)&sW[(v0 + j)*68 + k4*4];
      #pragma unroll
      for (int kk = 0; kk < 4; kk++) {
        float4 x4 = *(const float4*)&sY[(k4*4 + kk)*68 + tl0];
        #pragma unroll
        for (int j = 0; j < 4; j++) {
          float w = kk==0 ? wv[j].x : kk==1 ? wv[j].y : kk==2 ? wv[j].z : wv[j].w;
          acc[0][j] = fmaf(x4.x, w, acc[0][j]);
          acc[1][j] = fmaf(x4.y, w, acc[1][j]);
          acc[2][j] = fmaf(x4.z, w, acc[2][j]);
          acc[3][j] = fmaf(x4.w, w, acc[3][j]);
        }
      }
    }
    #pragma unroll
    for (int j = 0; j < 4; j++)
      *(float4*)&sU[(v0 + j)*68 + tl0] =
          make_float4(silu_f(acc[0][j]), silu_f(acc[1][j]),
                      silu_f(acc[2][j]), silu_f(acc[3][j]));
  }

  // Phase B: v[t][o] = bout[o] + sum_e u[e][t] * wout[o][e]  (o: 2 passes of 64)
  float s = 0.f, q = 0.f;
  for (int pass = 0; pass < 2; pass++) {
    __syncthreads();   // sU visible (pass0) / sW read-done
    for (int e = tid; e < 64*16; e += 256) {
      int row = e >> 4, c4 = e & 15;
      *(float4*)&sW[row*68 + c4*4] = *(const float4*)&wout[(pass*64 + row)*64 + c4*4];
    }
    __syncthreads();

    float a2[4][4];
    #pragma unroll
    for (int ti = 0; ti < 4; ti++)
      #pragma unroll
      for (int j = 0; j < 4; j++) a2[ti][j] = bout[pass*64 + v0 + j];

    for (int k4 = 0; k4 < 16; k4++) {
      float4 wv[4];
      #pragma unroll
      for (int j = 0; j < 4; j++)
        wv[j] = *(const float4*)&sW[(v0 + j)*68 + k4*4];
      #pragma unroll
      for (int kk = 0; kk < 4; kk++) {
        float4 x4 = *(const float4*)&sU[(k4*4 + kk)*68 + tl0];
        #pragma unroll
        for (int j = 0; j < 4; j++) {
          float w = kk==0 ? wv[j].x : kk==1 ? wv[j].y : kk==2 ? wv[j].z : wv[j].w;
          a2[0][j] = fmaf(x4.x, w, a2[0][j]);
          a2[1][j] = fmaf(x4.y, w, a2[1][j]);
          a2[2][j] = fmaf(x4.z, w, a2[2][j]);
          a2[3][j] = fmaf(x4.w, w, a2[3][j]);
        }
      }
    }

    #pragma unroll
    for (int ti = 0; ti < 4; ti++)
      #pragma unroll
      for (int j = 0; j < 4; j++) {
        float v = a2[ti][j];
        s += v;
        q = fmaf(v, v, q);
      }
    #pragma unroll
    for (int j = 0; j < 4; j++) {
      int o = pass*64 + v0 + j;
      *(float4*)&out[((b*128 + o)*32 + node)*256 + t0 + tl0] =
          make_float4(a2[0][j], a2[1][j], a2[2][j], a2[3][j]);
    }
  }

  sRs[tid] = s; sRq[tid] = q;
  __syncthreads();
  for (int st = 128; st > 0; st >>= 1) {
    if (tid < st) { sRs[tid] += sRs[tid + st]; sRq[tid] += sRq[tid + st]; }
    __syncthreads();
  }
  if (tid == 0) { PSTAT[bid*2] = sRs[0]; PSTAT[bid*2 + 1] = sRq[0]; }
}

// ---------------------------------------------------------------------------
// K5: LayerNorm in place on d_out (unchanged). grid 1024, block 256
// ---------------------------------------------------------------------------
__global__ __launch_bounds__(256) void k5_ln(
    const float* __restrict__ PSTAT, const float* __restrict__ lnw,
    const float* __restrict__ lnb, float* __restrict__ out)
{
  __shared__ float sLW[32*129], sLB[32*129];
  const int bid = blockIdx.x;
  const int r = bid >> 3, tb = bid & 7;
  const int b = r >> 5, node = r & 31;
  const int t0 = tb * 32;
  const int tid = threadIdx.x;

  float s = 0.f, q = 0.f;
  #pragma unroll
  for (int p = 0; p < 4; p++) {
    s += PSTAT[(r*4 + p)*2];
    q += PSTAT[(r*4 + p)*2 + 1];
  }
  const float mu = s * (1.f / 32768.f);
  const float var = q * (1.f / 32768.f) - mu * mu;
  const float rstd = rsqrtf(var + 1e-5f);

  for (int e = tid; e < 32*128; e += 256) {
    int t = e >> 7, o = e & 127;
    sLW[t*129 + o] = lnw[(t0 + t)*128 + o];
    sLB[t*129 + o] = lnb[(t0 + t)*128 + o];
  }
  __syncthreads();

  for (int n = 0; n < 16; n++) {
    int t = tid & 31;
    int o = (tid >> 5) + n*8;
    int idx = ((b*128 + o)*32 + node)*256 + t0 + t;
    float v = out[idx];
    out[idx] = fmaf((v - mu) * rstd, sLW[t*129 + o], sLB[t*129 + o]);
  }
}

// ---------------------------------------------------------------------------
extern "C" void kernel_launch(void* const* d_in, const int* in_sizes, int n_in,
                              void* d_out, int out_size, void* d_ws, size_t ws_size,
                              hipStream_t stream)
{
  (void)in_sizes; (void)n_in; (void)out_size; (void)ws_size;
  const float* inp   = (const float*)d_in[0];
  const float* w_in  = (const float*)d_in[1];
  const float* b_in  = (const float*)d_in[2];
  const float* ipw   = (const float*)d_in[3];
  const float* convw = (const float*)d_in[4];
  const float* convb = (const float*)d_in[5];
  const float* xpw   = (const float*)d_in[6];
  const float* dtw   = (const float*)d_in[7];
  const float* dtb   = (const float*)d_in[8];
  const float* alog  = (const float*)d_in[9];
  const float* Dp    = (const float*)d_in[10];
  const float* opw   = (const float*)d_in[11];
  const float* wout  = (const float*)d_in[12];
  const float* bout  = (const float*)d_in[13];
  const float* lnw   = (const float*)d_in[14];
  const float* lnb   = (const float*)d_in[15];

  float* ws = (float*)d_ws;
  float* XM    = ws + 0;
  float* Zb    = ws + 2097152;
  float* XC    = ws + 4194304;
  float* DELTA = ws + 6291456;
  float* BM    = ws + 8388608;
  float* CM    = ws + 12582912;
  float* YP    = ws + 16777216;   // 2 x 128 x 256 x 64
  float* PSTAT = ws + 20971520;   // 512 x 2
  float* out   = (float*)d_out;

  k1_proj<<<dim3(512), dim3(256), 0, stream>>>(inp, w_in, b_in, ipw, XM, Zb);
  k2_conv_xproj<<<dim3(512), dim3(256), 0, stream>>>(XM, convw, convb, xpw, dtw, dtb,
                                                     XC, DELTA, BM, CM);
  k3_scan<<<dim3(1024), dim3(256), 0, stream>>>(DELTA, XC, BM, CM, alog, YP);
  k4_post<<<dim3(512), dim3(256), 0, stream>>>(YP, XC, Zb, Dp, opw, wout, bout, out, PSTAT);
  k5_ln<<<dim3(1024), dim3(256), 0, stream>>>(PSTAT, lnw, lnb, out);
}

// Round 12
// 183.340 us; speedup vs baseline: 1.1584x; 1.0136x over previous
//
#include <hip/hip_runtime.h>
#include <math.h>

// Problem dims
// B=4, N_IN=128, NODE=32, L=256, N_HID=D_IN=64, D_STATE=128, DT_RANK=4, N_OUT=128
// R = B*NODE = 128 rows, each row independent; L sequential only in the scan (k3).
//
// R11 change: t-major layouts for DELTA/XC(scan copy)/Zb/YP ([r][d][t], t
// contiguous). k3's D/X become one float4 load per 4 t (was 8 scalar loads),
// y stored as one float4 per 4 t (was 4 scalar stores) -> VMEM ops per 4t
// 20 -> 11 and store-ack vmcnt pollution /4. R10 measured 98.5us VALUBusy 61%:
// residual stall = VMEM instr stream + store acks, not load latency alone.

__device__ __forceinline__ float silu_f(float v) { return v / (1.f + __expf(-v)); }
__device__ __forceinline__ float softplus_f(float v) { return v > 20.f ? v : log1pf(__expf(v)); }

#if __has_builtin(__builtin_amdgcn_exp2f)
#define EXP2N(x) __builtin_amdgcn_exp2f(x)
#else
#define EXP2N(x) __expf((x) * 0.6931471805599453f)   // 2^x = e^(x ln2), native
#endif

// ---------------------------------------------------------------------------
// K1: X = in @ w_in.T + b_in ; XZ = X @ in_proj_w.T -> XM [r][t][h], Zb [r][d][t]
// grid 512 = 128 rows x 4 t-tiles(64), block 256
// ---------------------------------------------------------------------------
__global__ __launch_bounds__(256) void k1_proj(
    const float* __restrict__ inp, const float* __restrict__ w_in,
    const float* __restrict__ b_in, const float* __restrict__ ipw,
    float* __restrict__ XM, float* __restrict__ Zb)
{
  __shared__ float sIN[128*64];   // [i=128][t=64]
  __shared__ float sW[64*68];     // staged weight tile [row][k], stride 68
  __shared__ float sXT[64*68];    // X transposed [h][t], stride 68
  const int bid = blockIdx.x;
  const int r = bid >> 2, tb = bid & 3;
  const int b = r >> 5, node = r & 31;
  const int t0 = tb * 64;
  const int tid = threadIdx.x;
  const int tg = tid & 15, vg = tid >> 4;
  const int tl0 = tg * 4, v0 = vg * 4;

  for (int e = tid; e < 128*64; e += 256) {
    int i = e >> 6, t = e & 63;
    sIN[e] = inp[((b*128 + i)*32 + node)*256 + t0 + t];
  }

  // Phase A: X[t][h] = b_in[h] + sum_i in[i][t] * w_in[h][i]   (K=128, 2 chunks)
  float acc[4][4];
  #pragma unroll
  for (int ti = 0; ti < 4; ti++)
    #pragma unroll
    for (int j = 0; j < 4; j++) acc[ti][j] = b_in[v0 + j];

  for (int kc = 0; kc < 2; kc++) {
    __syncthreads();   // sIN ready (kc=0) / sW read-done (kc=1)
    for (int e = tid; e < 64*16; e += 256) {
      int row = e >> 4, c4 = e & 15;
      *(float4*)&sW[row*68 + c4*4] = *(const float4*)&w_in[row*128 + kc*64 + c4*4];
    }
    __syncthreads();
    for (int k4 = 0; k4 < 16; k4++) {
      float4 wv[4];
      #pragma unroll
      for (int j = 0; j < 4; j++)
        wv[j] = *(const float4*)&sW[(v0 + j)*68 + k4*4];
      #pragma unroll
      for (int kk = 0; kk < 4; kk++) {
        float4 x4 = *(const float4*)&sIN[(kc*64 + k4*4 + kk)*64 + tl0];
        #pragma unroll
        for (int j = 0; j < 4; j++) {
          float w = kk==0 ? wv[j].x : kk==1 ? wv[j].y : kk==2 ? wv[j].z : wv[j].w;
          acc[0][j] = fmaf(x4.x, w, acc[0][j]);
          acc[1][j] = fmaf(x4.y, w, acc[1][j]);
          acc[2][j] = fmaf(x4.z, w, acc[2][j]);
          acc[3][j] = fmaf(x4.w, w, acc[3][j]);
        }
      }
    }
  }
  // stash X^T into sXT[h][t]
  #pragma unroll
  for (int j = 0; j < 4; j++)
    *(float4*)&sXT[(v0 + j)*68 + tl0] =
        make_float4(acc[0][j], acc[1][j], acc[2][j], acc[3][j]);

  // Phase B: XZ[t][c] = sum_h X[h][t] * ipw[c][h]   (c: 2 passes of 64)
  for (int pass = 0; pass < 2; pass++) {
    __syncthreads();   // sXT visible (pass0) / sW read-done
    for (int e = tid; e < 64*16; e += 256) {
      int row = e >> 4, c4 = e & 15;
      *(float4*)&sW[row*68 + c4*4] = *(const float4*)&ipw[(pass*64 + row)*64 + c4*4];
    }
    __syncthreads();

    float a2[4][4];
    #pragma unroll
    for (int ti = 0; ti < 4; ti++)
      #pragma unroll
      for (int j = 0; j < 4; j++) a2[ti][j] = 0.f;

    for (int k4 = 0; k4 < 16; k4++) {
      float4 wv[4];
      #pragma unroll
      for (int j = 0; j < 4; j++)
        wv[j] = *(const float4*)&sW[(v0 + j)*68 + k4*4];
      #pragma unroll
      for (int kk = 0; kk < 4; kk++) {
        float4 x4 = *(const float4*)&sXT[(k4*4 + kk)*68 + tl0];
        #pragma unroll
        for (int j = 0; j < 4; j++) {
          float w = kk==0 ? wv[j].x : kk==1 ? wv[j].y : kk==2 ? wv[j].z : wv[j].w;
          a2[0][j] = fmaf(x4.x, w, a2[0][j]);
          a2[1][j] = fmaf(x4.y, w, a2[1][j]);
          a2[2][j] = fmaf(x4.z, w, a2[2][j]);
          a2[3][j] = fmaf(x4.w, w, a2[3][j]);
        }
      }
    }

    if (pass == 0) {
      // XM [r][t][h] (unchanged layout; k2 conv reads d-contig)
      #pragma unroll
      for (int ti = 0; ti < 4; ti++)
        *(float4*)&XM[(r*256 + t0 + tl0 + ti)*64 + v0] =
            make_float4(a2[ti][0], a2[ti][1], a2[ti][2], a2[ti][3]);
    } else {
      // Zb_T [r][d][t]: per j, float4 over ti (t-contiguous)
      #pragma unroll
      for (int j = 0; j < 4; j++)
        *(float4*)&Zb[(r*64 + v0 + j)*256 + t0 + tl0] =
            make_float4(a2[0][j], a2[1][j], a2[2][j], a2[3][j]);
    }
  }
}

// ---------------------------------------------------------------------------
// K2: conv+silu -> XC_T [r][d][t] ; dbc = xc @ x_proj_w.T -> (dt | B | C) ;
//     delta=softplus(...) -> DELTA_T [r][d][t]
// grid 512 = 128 rows x 4 t-tiles(64), block 256
// ---------------------------------------------------------------------------
__global__ __launch_bounds__(256) void k2_conv_xproj(
    const float* __restrict__ XM, const float* __restrict__ convw,
    const float* __restrict__ convb, const float* __restrict__ xpw,
    const float* __restrict__ dtw, const float* __restrict__ dtb,
    float* __restrict__ XC, float* __restrict__ DELTA,
    float* __restrict__ BM, float* __restrict__ CM)
{
  __shared__ float sXM[65*64];    // [tt in -1..63][d]
  __shared__ float sXC[64*68];    // xc transposed [d][t], stride 68
  __shared__ float sW[64*68];     // staged x_proj_w tile
  __shared__ float sDT[64*5];     // dt[t][4], stride 5
  const int bid = blockIdx.x;
  const int r = bid >> 2, tb = bid & 3;
  const int t0 = tb * 64;
  const int tid = threadIdx.x;
  const int tg = tid & 15, vg = tid >> 4;
  const int tl0 = tg * 4, v0 = vg * 4;

  for (int e = tid; e < 65*64; e += 256) {
    int tt = e >> 6, d = e & 63;
    int tgl = t0 - 1 + tt;
    sXM[e] = (tgl < 0) ? 0.f : XM[(r*256 + tgl)*64 + d];
  }
  __syncthreads();

  for (int e = tid; e < 64*64; e += 256) {
    int t = e >> 6, d = e & 63;
    float c0 = convw[d*2], c1 = convw[d*2 + 1];
    float pre = fmaf(sXM[t*64 + d], c0, fmaf(sXM[(t+1)*64 + d], c1, convb[d]));
    sXC[d*68 + t] = silu_f(pre);
  }
  __syncthreads();   // sXC ready

  // XC_T write, t-major: lanes vary t -> LDS stride-1, global 256B contiguous
  for (int e = tid; e < 64*64; e += 256) {
    int d = e >> 6, t = e & 63;
    XC[(r*64 + d)*256 + t0 + t] = sXC[d*68 + t];
  }

  // dbc[t][j] = sum_d xc[d][t] * xpw[j][d],  j in 0..259 -> 5 passes of 64
  for (int pass = 0; pass < 5; pass++) {
    __syncthreads();   // sW read-done (and XC_T loop uses sXC read-only)
    for (int e = tid; e < 64*16; e += 256) {
      int row = e >> 4, c4 = e & 15;
      int grow = pass*64 + row;
      float4 w = (grow < 260) ? *(const float4*)&xpw[grow*64 + c4*4]
                              : make_float4(0.f, 0.f, 0.f, 0.f);
      *(float4*)&sW[row*68 + c4*4] = w;
    }
    __syncthreads();

    float acc[4][4];
    #pragma unroll
    for (int ti = 0; ti < 4; ti++)
      #pragma unroll
      for (int jj = 0; jj < 4; jj++) acc[ti][jj] = 0.f;

    for (int k4 = 0; k4 < 16; k4++) {
      float4 wv[4];
      #pragma unroll
      for (int jj = 0; jj < 4; jj++)
        wv[jj] = *(const float4*)&sW[(v0 + jj)*68 + k4*4];
      #pragma unroll
      for (int kk = 0; kk < 4; kk++) {
        float4 x4 = *(const float4*)&sXC[(k4*4 + kk)*68 + tl0];
        #pragma unroll
        for (int jj = 0; jj < 4; jj++) {
          float w = kk==0 ? wv[jj].x : kk==1 ? wv[jj].y : kk==2 ? wv[jj].z : wv[jj].w;
          acc[0][jj] = fmaf(x4.x, w, acc[0][jj]);
          acc[1][jj] = fmaf(x4.y, w, acc[1][jj]);
          acc[2][jj] = fmaf(x4.z, w, acc[2][jj]);
          acc[3][jj] = fmaf(x4.w, w, acc[3][jj]);
        }
      }
    }

    const int j0g = pass*64 + v0;   // multiple of 4; region bounds 4,132,260 are too
    if (j0g < 4) {
      #pragma unroll
      for (int ti = 0; ti < 4; ti++)
        #pragma unroll
        for (int jj = 0; jj < 4; jj++)
          sDT[(tl0 + ti)*5 + jj] = acc[ti][jj];
    } else if (j0g < 132) {
      #pragma unroll
      for (int ti = 0; ti < 4; ti++)
        *(float4*)&BM[(r*256 + t0 + tl0 + ti)*128 + (j0g - 4)] =
            make_float4(acc[ti][0], acc[ti][1], acc[ti][2], acc[ti][3]);
    } else if (j0g < 260) {
      #pragma unroll
      for (int ti = 0; ti < 4; ti++)
        *(float4*)&CM[(r*256 + t0 + tl0 + ti)*128 + (j0g - 132)] =
            make_float4(acc[ti][0], acc[ti][1], acc[ti][2], acc[ti][3]);
    }
  }
  __syncthreads();

  // DELTA_T write, t-major (sDT stride-5 read: banks (5t+j)%32, 2-way = free)
  for (int e = tid; e < 64*64; e += 256) {
    int d = e >> 6, t = e & 63;
    float4 w4 = *(const float4*)&dtw[d*4];
    float x = dtb[d];
    x = fmaf(sDT[t*5 + 0], w4.x, x);
    x = fmaf(sDT[t*5 + 1], w4.y, x);
    x = fmaf(sDT[t*5 + 2], w4.z, x);
    x = fmaf(sDT[t*5 + 3], w4.w, x);
    DELTA[(r*64 + d)*256 + t0 + t] = softplus_f(x);
  }
}

// ---------------------------------------------------------------------------
// K3: selective scan: zero-LDS, zero-barrier, DPP reduce, native exp2,
// t-major D/X (float4 per 4t), float4 y-store per 4t, depth-4 B/C pipeline.
// grid 1024: bid -> r (128 rows) x sc (2 s-chunks of 64) x dc (4 d-chunks of 16).
// block 256: dg = tid>>4 (16 d's), sg = tid&15 (16 s-groups of 4 states).
// YP layout: [sc][r][d][t].
// ---------------------------------------------------------------------------
__global__ __launch_bounds__(256) void k3_scan(
    const float* __restrict__ DELTA, const float* __restrict__ XC,
    const float* __restrict__ BM, const float* __restrict__ CM,
    const float* __restrict__ alog, float* __restrict__ YP)
{
  const int bid = blockIdx.x;
  const int r = bid & 127;
  const int rest = bid >> 7;
  const int sc = rest & 1;        // s-chunk: 64 states
  const int dc = rest >> 1;       // d-chunk: 16 channels
  const int tid = threadIdx.x;
  const int dg = tid >> 4;        // d within chunk
  const int sg = tid & 15;        // s-group (4 states each)
  const int sl0 = sg * 4;
  const int d = dc*16 + dg;
  const float LOG2E = 1.44269504f;

  float a2[4], h[4];
  #pragma unroll
  for (int j = 0; j < 4; j++) {
    a2[j] = -expf(alog[d*128 + sc*64 + sl0 + j]) * LOG2E;
    h[j] = 0.f;
  }

  const float* pB = BM    + r*256*128 + sc*64 + sl0;          // t-stride 128
  const float* pC = CM    + r*256*128 + sc*64 + sl0;
  const float* pD = DELTA + ((size_t)(r*64 + d))*256;         // t-contiguous
  const float* pX = XC    + ((size_t)(r*64 + d))*256;
  float*       pY = YP + ((size_t)((sc*128 + r)*64 + d))*256; // t-contiguous

  // depth-4 pipeline registers for B/C (named sets, rule #20)
  float4 vB0, vC0, vB1, vC1, vB2, vC2, vB3, vC3;

#define K3_LDBC(SET, T_) do { \
    vB##SET = *(const float4*)(pB + (T_)*128); \
    vC##SET = *(const float4*)(pC + (T_)*128); \
  } while (0)

#define K3_STEP(SET, DL_, XV_, YOUT_) do { \
    float dl = (DL_), xv = (XV_); \
    float4 Bv = vB##SET, Cv = vC##SET; \
    float u = dl * xv; \
    float y; \
    float dA0 = EXP2N(dl * a2[0]); \
    h[0] = fmaf(dA0, h[0], u * Bv.x); \
    y = h[0] * Cv.x; \
    float dA1 = EXP2N(dl * a2[1]); \
    h[1] = fmaf(dA1, h[1], u * Bv.y); \
    y = fmaf(h[1], Cv.y, y); \
    float dA2 = EXP2N(dl * a2[2]); \
    h[2] = fmaf(dA2, h[2], u * Bv.z); \
    y = fmaf(h[2], Cv.z, y); \
    float dA3 = EXP2N(dl * a2[3]); \
    h[3] = fmaf(dA3, h[3], u * Bv.w); \
    y = fmaf(h[3], Cv.w, y); \
    int yi; \
    yi = __builtin_amdgcn_update_dpp(__float_as_int(y), __float_as_int(y), \
                                     0x121, 0xf, 0xf, false); \
    y += __int_as_float(yi); \
    yi = __builtin_amdgcn_update_dpp(__float_as_int(y), __float_as_int(y), \
                                     0x122, 0xf, 0xf, false); \
    y += __int_as_float(yi); \
    yi = __builtin_amdgcn_update_dpp(__float_as_int(y), __float_as_int(y), \
                                     0x124, 0xf, 0xf, false); \
    y += __int_as_float(yi); \
    yi = __builtin_amdgcn_update_dpp(__float_as_int(y), __float_as_int(y), \
                                     0x128, 0xf, 0xf, false); \
    y += __int_as_float(yi); \
    (YOUT_) = y; \
  } while (0)

  float4 d4c = *(const float4*)(pD + 0);
  float4 x4c = *(const float4*)(pX + 0);
  K3_LDBC(0, 0); K3_LDBC(1, 1); K3_LDBC(2, 2); K3_LDBC(3, 3);

  for (int t = 0; t < 256; t += 4) {
    float4 d4n, x4n;
    if (t < 252) {
      d4n = *(const float4*)(pD + t + 4);
      x4n = *(const float4*)(pX + t + 4);
    }
    float4 yv;
    K3_STEP(0, d4c.x, x4c.x, yv.x); if (t < 252) K3_LDBC(0, t + 4);
    K3_STEP(1, d4c.y, x4c.y, yv.y); if (t < 252) K3_LDBC(1, t + 5);
    K3_STEP(2, d4c.z, x4c.z, yv.z); if (t < 252) K3_LDBC(2, t + 6);
    K3_STEP(3, d4c.w, x4c.w, yv.w); if (t < 252) K3_LDBC(3, t + 7);
    if (sg == 0)
      *(float4*)(pY + t) = yv;
    if (t < 252) { d4c = d4n; x4c = x4n; }
  }

#undef K3_LDBC
#undef K3_STEP
}

// ---------------------------------------------------------------------------
// K4: y=yp0+yp1 ; y2=y+xc*D ; y3=y2*silu(z) ; u=silu(y3@opw.T) ;
//     v=u@wout.T+bout -> d_out (pre-LN) + per-block stats
// grid 512 = 128 rows x 4 t-tiles(64), block 256
// Prologue t-major: YP/XC_T/Zb_T coalesced (t-contig), Dp[d] broadcast.
// ---------------------------------------------------------------------------
__global__ __launch_bounds__(256) void k4_post(
    const float* __restrict__ YP, const float* __restrict__ XC,
    const float* __restrict__ Zb, const float* __restrict__ Dp,
    const float* __restrict__ opw, const float* __restrict__ wout,
    const float* __restrict__ bout, float* __restrict__ out,
    float* __restrict__ PSTAT)
{
  __shared__ float sY[64*68];   // y3 transposed [d][t]
  __shared__ float sU[64*68];   // u transposed [e][t]
  __shared__ float sW[64*68];
  __shared__ float sRs[256], sRq[256];
  const int bid = blockIdx.x;
  const int r = bid >> 2, tb = bid & 3;
  const int b = r >> 5, node = r & 31;
  const int t0 = tb * 64;
  const int tid = threadIdx.x;
  const int tg = tid & 15, vg = tid >> 4;
  const int tl0 = tg * 4, v0 = vg * 4;

  for (int e = tid; e < 64*64; e += 256) {
    int d = e >> 6, t = e & 63;          // t-major
    int idxT = (r*64 + d)*256 + t0 + t;  // [r][d][t] arrays
    float y = YP[idxT] + YP[2097152 + idxT];
    float y2 = fmaf(XC[idxT], Dp[d], y);
    sY[d*68 + t] = y2 * silu_f(Zb[idxT]);
  }

  // Phase A: u[t][e'] = silu( sum_d y3[d][t] * opw[e'][d] )
  __syncthreads();
  for (int e = tid; e < 64*16; e += 256) {
    int row = e >> 4, c4 = e & 15;
    *(float4*)&sW[row*68 + c4*4] = *(const float4*)&opw[row*64 + c4*4];
  }
  __syncthreads();

  {
    float acc[4][4];
    #pragma unroll
    for (int ti = 0; ti < 4; ti++)
      #pragma unroll
      for (int j = 0; j < 4; j++) acc[ti][j] = 0.f;
    for (int k4 = 0; k4 < 16; k4++) {
      float4 wv[4];
      #pragma unroll
      for (int j = 0; j < 4; j++)
        wv[j] = *(const float4*)&sW[(v0 + j)*68 + k4*4];
      #pragma unroll
      for (int kk = 0; kk < 4; kk++) {
        float4 x4 = *(const float4*)&sY[(k4*4 + kk)*68 + tl0];
        #pragma unroll
        for (int j = 0; j < 4; j++) {
          float w = kk==0 ? wv[j].x : kk==1 ? wv[j].y : kk==2 ? wv[j].z : wv[j].w;
          acc[0][j] = fmaf(x4.x, w, acc[0][j]);
          acc[1][j] = fmaf(x4.y, w, acc[1][j]);
          acc[2][j] = fmaf(x4.z, w, acc[2][j]);
          acc[3][j] = fmaf(x4.w, w, acc[3][j]);
        }
      }
    }
    #pragma unroll
    for (int j = 0; j < 4; j++)
      *(float4*)&sU[(v0 + j)*68 + tl0] =
          make_float4(silu_f(acc[0][j]), silu_f(acc[1][j]),
                      silu_f(acc[2][j]), silu_f(acc[3][j]));
  }

  // Phase B: v[t][o] = bout[o] + sum_e u[e][t] * wout[o][e]  (o: 2 passes of 64)
  float s = 0.f, q = 0.f;
  for (int pass = 0; pass < 2; pass++) {
    __syncthreads();   // sU visible (pass0) / sW read-done
    for (int e = tid; e < 64*16; e += 256) {
      int row = e >> 4, c4 = e & 15;
      *(float4*)&sW[row*68 + c4*4] = *(const float4*)&wout[(pass*64 + row)*64 + c4*4];
    }
    __syncthreads();

    float a2[4][4];
    #pragma unroll
    for (int ti = 0; ti < 4; ti++)
      #pragma unroll
      for (int j = 0; j < 4; j++) a2[ti][j] = bout[pass*64 + v0 + j];

    for (int k4 = 0; k4 < 16; k4++) {
      float4 wv[4];
      #pragma unroll
      for (int j = 0; j < 4; j++)
        wv[j] = *(const float4*)&sW[(v0 + j)*68 + k4*4];
      #pragma unroll
      for (int kk = 0; kk < 4; kk++) {
        float4 x4 = *(const float4*)&sU[(k4*4 + kk)*68 + tl0];
        #pragma unroll
        for (int j = 0; j < 4; j++) {
          float w = kk==0 ? wv[j].x : kk==1 ? wv[j].y : kk==2 ? wv[j].z : wv[j].w;
          a2[0][j] = fmaf(x4.x, w, a2[0][j]);
          a2[1][j] = fmaf(x4.y, w, a2[1][j]);
          a2[2][j] = fmaf(x4.z, w, a2[2][j]);
          a2[3][j] = fmaf(x4.w, w, a2[3][j]);
        }
      }
    }

    #pragma unroll
    for (int ti = 0; ti < 4; ti++)
      #pragma unroll
      for (int j = 0; j < 4; j++) {
        float v = a2[ti][j];
        s += v;
        q = fmaf(v, v, q);
      }
    #pragma unroll
    for (int j = 0; j < 4; j++) {
      int o = pass*64 + v0 + j;
      *(float4*)&out[((b*128 + o)*32 + node)*256 + t0 + tl0] =
          make_float4(a2[0][j], a2[1][j], a2[2][j], a2[3][j]);
    }
  }

  sRs[tid] = s; sRq[tid] = q;
  __syncthreads();
  for (int st = 128; st > 0; st >>= 1) {
    if (tid < st) { sRs[tid] += sRs[tid + st]; sRq[tid] += sRq[tid + st]; }
    __syncthreads();
  }
  if (tid == 0) { PSTAT[bid*2] = sRs[0]; PSTAT[bid*2 + 1] = sRq[0]; }
}

// ---------------------------------------------------------------------------
// K5: LayerNorm in place on d_out (unchanged). grid 1024, block 256
// ---------------------------------------------------------------------------
__global__ __launch_bounds__(256) void k5_ln(
    const float* __restrict__ PSTAT, const float* __restrict__ lnw,
    const float* __restrict__ lnb, float* __restrict__ out)
{
  __shared__ float sLW[32*129], sLB[32*129];
  const int bid = blockIdx.x;
  const int r = bid >> 3, tb = bid & 7;
  const int b = r >> 5, node = r & 31;
  const int t0 = tb * 32;
  const int tid = threadIdx.x;

  float s = 0.f, q = 0.f;
  #pragma unroll
  for (int p = 0; p < 4; p++) {
    s += PSTAT[(r*4 + p)*2];
    q += PSTAT[(r*4 + p)*2 + 1];
  }
  const float mu = s * (1.f / 32768.f);
  const float var = q * (1.f / 32768.f) - mu * mu;
  const float rstd = rsqrtf(var + 1e-5f);

  for (int e = tid; e < 32*128; e += 256) {
    int t = e >> 7, o = e & 127;
    sLW[t*129 + o] = lnw[(t0 + t)*128 + o];
    sLB[t*129 + o] = lnb[(t0 + t)*128 + o];
  }
  __syncthreads();

  for (int n = 0; n < 16; n++) {
    int t = tid & 31;
    int o = (tid >> 5) + n*8;
    int idx = ((b*128 + o)*32 + node)*256 + t0 + t;
    float v = out[idx];
    out[idx] = fmaf((v - mu) * rstd, sLW[t*129 + o], sLB[t*129 + o]);
  }
}

// ---------------------------------------------------------------------------
extern "C" void kernel_launch(void* const* d_in, const int* in_sizes, int n_in,
                              void* d_out, int out_size, void* d_ws, size_t ws_size,
                              hipStream_t stream)
{
  (void)in_sizes; (void)n_in; (void)out_size; (void)ws_size;
  const float* inp   = (const float*)d_in[0];
  const float* w_in  = (const float*)d_in[1];
  const float* b_in  = (const float*)d_in[2];
  const float* ipw   = (const float*)d_in[3];
  const float* convw = (const float*)d_in[4];
  const float* convb = (const float*)d_in[5];
  const float* xpw   = (const float*)d_in[6];
  const float* dtw   = (const float*)d_in[7];
  const float* dtb   = (const float*)d_in[8];
  const float* alog  = (const float*)d_in[9];
  const float* Dp    = (const float*)d_in[10];
  const float* opw   = (const float*)d_in[11];
  const float* wout  = (const float*)d_in[12];
  const float* bout  = (const float*)d_in[13];
  const float* lnw   = (const float*)d_in[14];
  const float* lnb   = (const float*)d_in[15];

  float* ws = (float*)d_ws;
  float* XM    = ws + 0;          // [r][t][h]
  float* Zb    = ws + 2097152;    // [r][d][t]  (transposed, R11)
  float* XC    = ws + 4194304;    // [r][d][t]  (transposed, R11)
  float* DELTA = ws + 6291456;    // [r][d][t]  (transposed, R11)
  float* BM    = ws + 8388608;    // [r][t][s]
  float* CM    = ws + 12582912;   // [r][t][s]
  float* YP    = ws + 16777216;   // [sc][r][d][t]  (transposed, R11)
  float* PSTAT = ws + 20971520;   // 512 x 2
  float* out   = (float*)d_out;

  k1_proj<<<dim3(512), dim3(256), 0, stream>>>(inp, w_in, b_in, ipw, XM, Zb);
  k2_conv_xproj<<<dim3(512), dim3(256), 0, stream>>>(XM, convw, convb, xpw, dtw, dtb,
                                                     XC, DELTA, BM, CM);
  k3_scan<<<dim3(1024), dim3(256), 0, stream>>>(DELTA, XC, BM, CM, alog, YP);
  k4_post<<<dim3(512), dim3(256), 0, stream>>>(YP, XC, Zb, Dp, opw, wout, bout, out, PSTAT);
  k5_ln<<<dim3(1024), dim3(256), 0, stream>>>(PSTAT, lnw, lnb, out);
}